// Round 13
// baseline (453.775 us; speedup 1.0000x reference)
//
#include <hip/hip_runtime.h>
#include <hip/hip_bf16.h>

#define NN 50000
#define NE 800000
#define HCn 256
#define LATn 64

typedef short bf16x4 __attribute__((ext_vector_type(4)));
typedef short bf16x8 __attribute__((ext_vector_type(8)));
typedef float f32x4 __attribute__((ext_vector_type(4)));

__device__ __forceinline__ short f2b(float f) {
    __hip_bfloat16 h = __float2bfloat16(f);   // RNE
    return __builtin_bit_cast(short, h);
}
__device__ __forceinline__ float b2f(short s) {
    return __bfloat162float(__builtin_bit_cast(__hip_bfloat16, s));
}

// single-instruction lane swizzle (BitMode xor; works within 32-lane halves).
// DS-pipe op: overlaps with other waves' VALU work (measured r8 vs r10: beats DPP).
#define SWZF(v, pat) __builtin_bit_cast(float, __builtin_amdgcn_ds_swizzle(__builtin_bit_cast(int, v), pat))

#define C04L2E 0.5770780163555854f   // 0.4 * log2(e)
#define C06L2E 0.8656170245333781f   // 0.6 * log2(e)
#define DEFER_THR 8.0f               // defer-max threshold (log2 units)

// ---------------- CSR build ----------------
__global__ void hist_kernel(const int* __restrict__ dst, int* __restrict__ counts) {
    int e = blockIdx.x * 256 + threadIdx.x;
    if (e < NE) atomicAdd(&counts[dst[e]], 1);
}

__global__ __launch_bounds__(1024) void scan1_kernel(int* __restrict__ counts,
                                                     int* __restrict__ blocksum) {
    const int g = blockIdx.x * 1024 + threadIdx.x;
    const int lane = threadIdx.x & 63;
    const int wv = threadIdx.x >> 6;            // 0..15
    int v = (g < NN) ? counts[g] : 0;
    int s = v;
#pragma unroll
    for (int d = 1; d < 64; d <<= 1) {
        int t = __shfl_up(s, d, 64);
        if (lane >= d) s += t;
    }
    __shared__ int wsum[16];
    if (lane == 63) wsum[wv] = s;
    __syncthreads();
    if (threadIdx.x == 0) {
        int run = 0;
#pragma unroll
        for (int q = 0; q < 16; ++q) { int t = wsum[q]; wsum[q] = run; run += t; }
        blocksum[blockIdx.x] = run;
    }
    __syncthreads();
    int excl = s - v + wsum[wv];
    if (g < NN) counts[g] = excl;
}

__global__ void scan2_kernel(int* __restrict__ blocksum, int* __restrict__ offsets, int nblk) {
    const int lane = threadIdx.x;               // 64 threads
    int v = (lane < nblk) ? blocksum[lane] : 0;
    int s = v;
#pragma unroll
    for (int d = 1; d < 64; d <<= 1) {
        int t = __shfl_up(s, d, 64);
        if (lane >= d) s += t;
    }
    if (lane < nblk) blocksum[lane] = s - v;    // exclusive
    if (lane == 0) offsets[NN] = NE;
}

__global__ __launch_bounds__(1024) void scan3_kernel(const int* __restrict__ counts,
                                                     const int* __restrict__ blocksum,
                                                     int* __restrict__ offsets,
                                                     int* __restrict__ cursor) {
    const int g = blockIdx.x * 1024 + threadIdx.x;
    if (g < NN) {
        int v = counts[g] + blocksum[blockIdx.x];
        offsets[g] = v;
        cursor[g]  = v;
    }
}

__global__ void scatter_kernel(const int* __restrict__ src, const int* __restrict__ dst,
                               int* __restrict__ cursor, int* __restrict__ csr_src) {
    int e = blockIdx.x * 256 + threadIdx.x;
    if (e < NE) {
        int p = atomicAdd(&cursor[dst[e]], 1);
        csr_src[p] = src[e];
    }
}

// ---------------- pack weights to bf16, TRANSPOSED: Wbt[n][k] = W[k][n] ----------------
__global__ void pack_w_kernel(const float* __restrict__ Wl1, const float* __restrict__ Wr1,
                              const float* __restrict__ Wl2, const float* __restrict__ Wr2,
                              const float* __restrict__ Wmu, const float* __restrict__ Wlv,
                              const float* __restrict__ bmu, const float* __restrict__ blv,
                              short* __restrict__ Wb1t, short* __restrict__ Wb2t,
                              short* __restrict__ Wb3t, float* __restrict__ bias3) {
    int i = blockIdx.x * 256 + threadIdx.x;
    const int S1 = 512 * 256, S2 = 2 * S1, S3 = S2 + 128 * 256;
    if (i < S1) {
        int c = i >> 8, k = i & 255;
        float v = (c < 256) ? Wl1[k * 256 + c] : Wr1[k * 256 + (c - 256)];
        Wb1t[i] = f2b(v);
    } else if (i < S2) {
        int j = i - S1; int c = j >> 8, k = j & 255;
        float v = (c < 256) ? Wl2[k * 256 + c] : Wr2[k * 256 + (c - 256)];
        Wb2t[j] = f2b(v);
    } else if (i < S3) {
        int j = i - S2; int c = j >> 8, k = j & 255;
        float v = (c < 64) ? Wmu[k * 64 + c] : Wlv[k * 64 + (c - 64)];
        Wb3t[j] = f2b(v);
    } else if (i < S3 + 128) {
        int c = i - S3;
        bias3[c] = (c < 64) ? bmu[c] : blv[c - 64];
    }
}

// ---------------- GEMM: A[M,256] @ W[256,Nc], Wbt[Nc,256] transposed ----------------
// 64-row blocks, no column grid; A frags in registers; loop over NCT 64-col LDS sub-tiles.
// OUT_MODE 0 (layer): cols 0..255 -> f32 to xlf[N,256]; cols 256..511 -> bf16 to xrh[N,256].
//   xrh may alias A (in-place): A frags are loaded pre-barrier, xr writes are >=4 barriers later.
// OUT_MODE 1 (heads): f32 out split 64|64 + bias.
// ATT=1: fuse a_arr[row][h] = C06L2E * att[h,:]·xl[row,:] for ct<4 (from f32 acc).
template<int A_F32, int OUT_MODE, int NCT, int ATT>
__global__ __launch_bounds__(256) void gemm_k(
    const void* __restrict__ Ap, const short* __restrict__ Wbt,
    float* __restrict__ outF, short* __restrict__ outB, const float* __restrict__ bias,
    const float* __restrict__ att, float* __restrict__ a_arr)
{
    __shared__ short Bs[64 * 256];   // 32 KB, XOR-swizzled chunks (chunk = 8 shorts = 16B)
    const int t = threadIdx.x;
    const int w = t >> 6, lane = t & 63;
    const int row0 = blockIdx.x * 64;
    const int arow = lane & 15, kq = lane >> 4;
    const int xorc = arow & 7;

    // load A fragments once: row w*16+arow, k-chunks kc*32 + kq*8
    bf16x8 af[8];
    {
        int r0 = row0 + w * 16 + arow; if (r0 > NN - 1) r0 = NN - 1;
        if (A_F32) {
            const float* A = (const float*)Ap;
            const float* base = A + (long)r0 * 256 + kq * 8;
#pragma unroll
            for (int kc = 0; kc < 8; ++kc) {
                const f32x4* q = reinterpret_cast<const f32x4*>(base + kc * 32);
                f32x4 u0 = q[0], u1 = q[1];
#pragma unroll
                for (int j = 0; j < 4; ++j) { af[kc][j] = f2b(u0[j]); af[kc][4 + j] = f2b(u1[j]); }
            }
        } else {
            const short* A = (const short*)Ap;
            const short* base = A + (long)r0 * 256 + kq * 8;
#pragma unroll
            for (int kc = 0; kc < 8; ++kc)
                af[kc] = *reinterpret_cast<const bf16x8*>(base + kc * 32);
        }
    }

    const int sn = t >> 2;           // staging row 0..63
    const int cq = t & 3;            // 4 threads per row

#pragma unroll 1
    for (int ct = 0; ct < NCT; ++ct) {
        // stage B sub-panel: Bs[n][chunk^(n&7)] = Wbt[ct*64+n][chunk]
        {
            const short* wp = Wbt + (long)(ct * 64 + sn) * 256;
            short* bp = &Bs[sn * 256];
            const int sx = sn & 7;
#pragma unroll
            for (int r = 0; r < 8; ++r) {
                int c = cq + r * 4;      // chunk 0..31
                bf16x8 v = *reinterpret_cast<const bf16x8*>(wp + c * 8);
                *reinterpret_cast<bf16x8*>(bp + ((c ^ sx) * 8)) = v;
            }
        }
        __syncthreads();

        f32x4 acc[4];
#pragma unroll
        for (int b = 0; b < 4; ++b) acc[b] = (f32x4){0.f, 0.f, 0.f, 0.f};

#pragma unroll
        for (int kc = 0; kc < 8; ++kc) {
            const int chunk = (kc * 4 + kq) ^ xorc;
#pragma unroll
            for (int nt = 0; nt < 4; ++nt) {
                bf16x8 b = *reinterpret_cast<const bf16x8*>(&Bs[(nt * 16 + arow) * 256 + chunk * 8]);
                acc[nt] = __builtin_amdgcn_mfma_f32_16x16x32_bf16(af[kc], b, acc[nt], 0, 0, 0);
            }
        }

        // fused att_pre: ct<4 covers xl head ct (cols ct*64 .. ct*64+63)
        if (ATT && ct < 4) {
            float av[4];
#pragma unroll
            for (int nt = 0; nt < 4; ++nt) av[nt] = att[ct * 64 + nt * 16 + arow];
#pragma unroll
            for (int r = 0; r < 4; ++r) {
                float pd = av[0] * acc[0][r] + av[1] * acc[1][r]
                         + av[2] * acc[2][r] + av[3] * acc[3][r];
                pd += SWZF(pd, 0x041F);
                pd += SWZF(pd, 0x081F);
                pd += SWZF(pd, 0x101F);
                pd += SWZF(pd, 0x201F);
                int grow = row0 + w * 16 + kq * 4 + r;
                if (arow == 0 && grow < NN) a_arr[grow * 4 + ct] = pd * C06L2E;
            }
        }

        // write out: C/D layout col = arow, row = kq*4 + r
#pragma unroll
        for (int nt = 0; nt < 4; ++nt) {
            int gcol = ct * 64 + nt * 16 + arow;
#pragma unroll
            for (int r = 0; r < 4; ++r) {
                int grow = row0 + w * 16 + kq * 4 + r;
                if (grow < NN) {
                    float v = acc[nt][r];
                    if (OUT_MODE == 0) {
                        if (ct < 4) outF[(long)grow * 256 + gcol] = v;            // xl f32
                        else        outB[(long)grow * 256 + (gcol - 256)] = f2b(v); // xr bf16
                    } else {
                        v += bias[gcol];
                        if (gcol < 64) outF[(long)grow * 64 + gcol] = v;
                        else           outF[(long)NN * 64 + (long)grow * 64 + (gcol - 64)] = v;
                    }
                }
            }
        }
        __syncthreads();   // Bs reads done before next stage
    }
}

// ---------------- fused GATv2: f32 xl gather (no cvt), bf16 xr, index prefetch ----------------
// score (log2 domain, dst-constant term dropped): s = a[j][h] + sum_c (0.4*log2e*att_c)*|xl_jc+xr_ic|
__device__ __forceinline__ void edge_abs_score(const float* __restrict__ xlf, int j, int c4,
                                               const float* xr, const f32x4& attv04,
                                               float* xf, float& s) {
    f32x4 v = *reinterpret_cast<const f32x4*>(xlf + (long)j * 256 + c4);
    s = 0.f;
#pragma unroll
    for (int k = 0; k < 4; ++k) {
        xf[k] = v[k];
        float vv = v[k] + xr[k];
        s = fmaf(attv04[k], fabsf(vv), s);   // abs = free input modifier
    }
    // 16-lane head-group reduce: xor 1,2,4,8 (DS pipe, overlaps other waves' VALU)
    s += SWZF(s, 0x041F);
    s += SWZF(s, 0x081F);
    s += SWZF(s, 0x101F);
    s += SWZF(s, 0x201F);
}

__global__ __launch_bounds__(256) void gat_node_kernel(
    const float* __restrict__ xlf, const short* __restrict__ xrh,
    const float* __restrict__ aarr,
    const int* __restrict__ offsets, const int* __restrict__ csr_src,
    const float* __restrict__ att, const float* __restrict__ bias,
    const float* __restrict__ ln_g, const float* __restrict__ ln_b,
    short* __restrict__ hout)   // hout == xrh (in-place; own row only)
{
    const int i = blockIdx.x * 4 + (threadIdx.x >> 6);
    const int lane = threadIdx.x & 63;
    const int h  = lane >> 4;
    const int c4 = h * 64 + (lane & 15) * 4;   // head*64 + 4 channels

    f32x4 attv04 = *reinterpret_cast<const f32x4*>(att + c4);
#pragma unroll
    for (int k = 0; k < 4; ++k) attv04[k] *= C04L2E;

    float xr[4];
    {
        bf16x4 v = *reinterpret_cast<const bf16x4*>(xrh + (long)i * 256 + c4);
#pragma unroll
        for (int k = 0; k < 4; ++k) xr[k] = b2f(v[k]);
    }

    const int p0 = offsets[i], p1 = offsets[i + 1];

    // prefetch first pass's indices (clamped, branchless)
    int pp = p0 + (lane & 3);
    int jl = csr_src[pp < NE ? pp : NE - 1];

    float m, l;
    float acc[4];
    // self loop first
    {
        float aj = aarr[i * 4 + h];
        float xf[4], s;
        edge_abs_score(xlf, i, c4, xr, attv04, xf, s);
        m = s + aj; l = 1.f;
#pragma unroll
        for (int k = 0; k < 4; ++k) acc[k] = xf[k];
    }

    int p = p0;
    for (; p + 4 <= p1; p += 4) {
        int j0 = __builtin_amdgcn_readlane(jl, 0);
        int j1 = __builtin_amdgcn_readlane(jl, 1);
        int j2 = __builtin_amdgcn_readlane(jl, 2);
        int j3 = __builtin_amdgcn_readlane(jl, 3);
        // prefetch next pass (or tail) indices while this pass computes
        int pn = p + 4 + (lane & 3);
        jl = csr_src[pn < p1 ? pn : (p1 > 0 ? p1 - 1 : 0)];
        float a0 = aarr[j0 * 4 + h], a1 = aarr[j1 * 4 + h];
        float a2 = aarr[j2 * 4 + h], a3 = aarr[j3 * 4 + h];
        float x0[4], x1[4], x2[4], x3[4], s0, s1, s2, s3;
        edge_abs_score(xlf, j0, c4, xr, attv04, x0, s0);
        edge_abs_score(xlf, j1, c4, xr, attv04, x1, s1);
        edge_abs_score(xlf, j2, c4, xr, attv04, x2, s2);
        edge_abs_score(xlf, j3, c4, xr, attv04, x3, s3);
        s0 += a0; s1 += a1; s2 += a2; s3 += a3;
        float sm = fmaxf(fmaxf(s0, s1), fmaxf(s2, s3));
        if (__all(sm <= m + DEFER_THR)) {
            float e0 = __builtin_amdgcn_exp2f(s0 - m);
            float e1 = __builtin_amdgcn_exp2f(s1 - m);
            float e2 = __builtin_amdgcn_exp2f(s2 - m);
            float e3 = __builtin_amdgcn_exp2f(s3 - m);
            l += (e0 + e1) + (e2 + e3);
#pragma unroll
            for (int k = 0; k < 4; ++k)
                acc[k] = fmaf(e0, x0[k], fmaf(e1, x1[k], fmaf(e2, x2[k], fmaf(e3, x3[k], acc[k]))));
        } else {
            float mn = fmaxf(m, sm);
            float corr = __builtin_amdgcn_exp2f(m - mn);
            float e0 = __builtin_amdgcn_exp2f(s0 - mn);
            float e1 = __builtin_amdgcn_exp2f(s1 - mn);
            float e2 = __builtin_amdgcn_exp2f(s2 - mn);
            float e3 = __builtin_amdgcn_exp2f(s3 - mn);
            l = fmaf(l, corr, (e0 + e1) + (e2 + e3));
#pragma unroll
            for (int k = 0; k < 4; ++k)
                acc[k] = fmaf(acc[k], corr,
                         fmaf(e0, x0[k], fmaf(e1, x1[k], fmaf(e2, x2[k], e3 * x3[k]))));
            m = mn;
        }
    }
    // tail 0..3 edges: indices already resident in jl (lanes 0..rem-1)
    int rem = p1 - p;
    for (int tq = 0; tq < rem; ++tq) {
        int j = __builtin_amdgcn_readlane(jl, tq);
        float aj = aarr[j * 4 + h];
        float xa[4], sa;
        edge_abs_score(xlf, j, c4, xr, attv04, xa, sa);
        sa += aj;
        if (__all(sa <= m + DEFER_THR)) {
            float ex = __builtin_amdgcn_exp2f(sa - m);
            l += ex;
#pragma unroll
            for (int k = 0; k < 4; ++k) acc[k] = fmaf(ex, xa[k], acc[k]);
        } else {
            float mn = fmaxf(m, sa);
            float corr = __builtin_amdgcn_exp2f(m - mn);
            float ex = __builtin_amdgcn_exp2f(sa - mn);
            l = fmaf(l, corr, ex);
#pragma unroll
            for (int k = 0; k < 4; ++k) acc[k] = fmaf(acc[k], corr, ex * xa[k]);
            m = mn;
        }
    }

    float inv = 1.f / l;
    f32x4 bv = *reinterpret_cast<const f32x4*>(bias + c4);
    float out[4], s1 = 0.f, s2 = 0.f;
#pragma unroll
    for (int k = 0; k < 4; ++k) {
        out[k] = acc[k] * inv + bv[k];
        s1 += out[k];
        s2 += out[k] * out[k];
    }
    // LN over 256 channels: full-wave butterfly (swizzle xor 1..16, shfl xor 32)
    s1 += SWZF(s1, 0x041F); s2 += SWZF(s2, 0x041F);
    s1 += SWZF(s1, 0x081F); s2 += SWZF(s2, 0x081F);
    s1 += SWZF(s1, 0x101F); s2 += SWZF(s2, 0x101F);
    s1 += SWZF(s1, 0x201F); s2 += SWZF(s2, 0x201F);
    s1 += SWZF(s1, 0x401F); s2 += SWZF(s2, 0x401F);
    s1 += __shfl_xor(s1, 32, 64);
    s2 += __shfl_xor(s2, 32, 64);
    float mu  = s1 * (1.f / 256.f);
    float var = s2 * (1.f / 256.f) - mu * mu;
    float rs  = rsqrtf(var + 1e-5f);
    f32x4 gv  = *reinterpret_cast<const f32x4*>(ln_g + c4);
    f32x4 bbv = *reinterpret_cast<const f32x4*>(ln_b + c4);
    bf16x4 o;
#pragma unroll
    for (int k = 0; k < 4; ++k) {
        float y = (out[k] - mu) * rs * gv[k] + bbv[k];
        y = y > 0.f ? y : expm1f(y);                    // ELU
        o[k] = f2b(y);
    }
    *reinterpret_cast<bf16x4*>(hout + (long)i * 256 + c4) = o;
}

// ---------------- launch ----------------
extern "C" void kernel_launch(void* const* d_in, const int* in_sizes, int n_in,
                              void* d_out, int out_size, void* d_ws, size_t ws_size,
                              hipStream_t stream) {
    const float* x    = (const float*)d_in[0];
    const int*   ei   = (const int*)d_in[1];
    const float* Wl1  = (const float*)d_in[2];
    const float* Wr1  = (const float*)d_in[3];
    const float* att1 = (const float*)d_in[4];
    const float* b1   = (const float*)d_in[5];
    const float* ln1g = (const float*)d_in[6];
    const float* ln1b = (const float*)d_in[7];
    const float* Wl2  = (const float*)d_in[8];
    const float* Wr2  = (const float*)d_in[9];
    const float* att2 = (const float*)d_in[10];
    const float* b2   = (const float*)d_in[11];
    const float* ln2g = (const float*)d_in[12];
    const float* ln2b = (const float*)d_in[13];
    const float* Wmu  = (const float*)d_in[14];
    const float* bmu  = (const float*)d_in[15];
    const float* Wlv  = (const float*)d_in[16];
    const float* blv  = (const float*)d_in[17];

    // workspace layout (~83 MB)
    float* xlf   = (float*)d_ws;                       // [N,256] f32 xl
    short* xrh   = (short*)(xlf + (long)NN * 256);     // [N,256] bf16: xr, then h (in-place)
    short* Wb1t  = xrh + (long)NN * 256;               // 512*256
    short* Wb2t  = Wb1t + 512 * 256;
    short* Wb3t  = Wb2t + 512 * 256;                   // 128*256
    float* bias3 = (float*)(Wb3t + 128 * 256);         // 128
    int* counts  = (int*)(bias3 + 128);
    int* offsets = counts + NN;                        // N+1
    int* cursor  = offsets + NN + 1;
    int* csr_src = cursor + NN;                        // E
    int* blocksum = csr_src + NE;                      // 64
    float* a_arr = (float*)(blocksum + 64);            // [N,4]

    const int* src = ei;
    const int* dst = ei + NE;

    const int NBLK = (NN + 1023) / 1024;               // 49

    // CSR by dst (parallel scan)
    hipMemsetAsync(counts, 0, NN * sizeof(int), stream);
    hist_kernel<<<(NE + 255) / 256, 256, 0, stream>>>(dst, counts);
    scan1_kernel<<<NBLK, 1024, 0, stream>>>(counts, blocksum);
    scan2_kernel<<<1, 64, 0, stream>>>(blocksum, offsets, NBLK);
    scan3_kernel<<<NBLK, 1024, 0, stream>>>(counts, blocksum, offsets, cursor);
    scatter_kernel<<<(NE + 255) / 256, 256, 0, stream>>>(src, dst, cursor, csr_src);

    // pack transposed weights
    pack_w_kernel<<<1153, 256, 0, stream>>>(Wl1, Wr1, Wl2, Wr2, Wmu, Wlv, bmu, blv,
                                            Wb1t, Wb2t, Wb3t, bias3);

    const int GM = (NN + 63) / 64;     // 782 row-blocks

    // layer 1 (A = x f32; writes xlf f32 + xr bf16; att_pre fused)
    gemm_k<1, 0, 8, 1><<<GM, 256, 0, stream>>>(x, Wb1t, xlf, xrh, nullptr, att1, a_arr);
    gat_node_kernel<<<NN / 4, 256, 0, stream>>>(xlf, xrh, a_arr, offsets, csr_src,
                                                att1, b1, ln1g, ln1b, xrh);
    // layer 2 (A = h in xrh; in-place xr overwrite is barrier-safe)
    gemm_k<0, 0, 8, 1><<<GM, 256, 0, stream>>>(xrh, Wb2t, xlf, xrh, nullptr, att2, a_arr);
    gat_node_kernel<<<NN / 4, 256, 0, stream>>>(xlf, xrh, a_arr, offsets, csr_src,
                                                att2, b2, ln2g, ln2b, xrh);
    // heads: [mu|logvar]
    gemm_k<0, 1, 2, 0><<<GM, 256, 0, stream>>>(xrh, Wb3t, (float*)d_out, nullptr, bias3,
                                               nullptr, nullptr);
}

// Round 14
// 332.144 us; speedup vs baseline: 1.3662x; 1.3662x over previous
//
#include <hip/hip_runtime.h>
#include <hip/hip_bf16.h>

#define NN 50000
#define NE 800000
#define HCn 256
#define LATn 64

typedef short bf16x4 __attribute__((ext_vector_type(4)));
typedef short bf16x8 __attribute__((ext_vector_type(8)));
typedef float f32x4 __attribute__((ext_vector_type(4)));

__device__ __forceinline__ short f2b(float f) {
    __hip_bfloat16 h = __float2bfloat16(f);   // RNE
    return __builtin_bit_cast(short, h);
}
__device__ __forceinline__ float b2f(short s) {
    return __bfloat162float(__builtin_bit_cast(__hip_bfloat16, s));
}

// single-instruction lane swizzle (BitMode xor; works within 32-lane halves).
// DS-pipe op: overlaps with other waves' VALU work (measured r8 vs r10: beats DPP).
#define SWZF(v, pat) __builtin_bit_cast(float, __builtin_amdgcn_ds_swizzle(__builtin_bit_cast(int, v), pat))

#define C04L2E 0.5770780163555854f   // 0.4 * log2(e)
#define C06L2E 0.8656170245333781f   // 0.6 * log2(e)
#define DEFER_THR 8.0f               // defer-max threshold (log2 units)

// ---------------- CSR build ----------------
__global__ void hist_kernel(const int* __restrict__ dst, int* __restrict__ counts) {
    int e = blockIdx.x * 256 + threadIdx.x;
    if (e < NE) atomicAdd(&counts[dst[e]], 1);
}

__global__ __launch_bounds__(1024) void scan1_kernel(int* __restrict__ counts,
                                                     int* __restrict__ blocksum) {
    const int g = blockIdx.x * 1024 + threadIdx.x;
    const int lane = threadIdx.x & 63;
    const int wv = threadIdx.x >> 6;            // 0..15
    int v = (g < NN) ? counts[g] : 0;
    int s = v;
#pragma unroll
    for (int d = 1; d < 64; d <<= 1) {
        int t = __shfl_up(s, d, 64);
        if (lane >= d) s += t;
    }
    __shared__ int wsum[16];
    if (lane == 63) wsum[wv] = s;
    __syncthreads();
    if (threadIdx.x == 0) {
        int run = 0;
#pragma unroll
        for (int q = 0; q < 16; ++q) { int t = wsum[q]; wsum[q] = run; run += t; }
        blocksum[blockIdx.x] = run;
    }
    __syncthreads();
    int excl = s - v + wsum[wv];
    if (g < NN) counts[g] = excl;
}

__global__ void scan2_kernel(int* __restrict__ blocksum, int* __restrict__ offsets, int nblk) {
    const int lane = threadIdx.x;               // 64 threads
    int v = (lane < nblk) ? blocksum[lane] : 0;
    int s = v;
#pragma unroll
    for (int d = 1; d < 64; d <<= 1) {
        int t = __shfl_up(s, d, 64);
        if (lane >= d) s += t;
    }
    if (lane < nblk) blocksum[lane] = s - v;    // exclusive
    if (lane == 0) offsets[NN] = NE;
}

__global__ __launch_bounds__(1024) void scan3_kernel(const int* __restrict__ counts,
                                                     const int* __restrict__ blocksum,
                                                     int* __restrict__ offsets,
                                                     int* __restrict__ cursor) {
    const int g = blockIdx.x * 1024 + threadIdx.x;
    if (g < NN) {
        int v = counts[g] + blocksum[blockIdx.x];
        offsets[g] = v;
        cursor[g]  = v;
    }
}

__global__ void scatter_kernel(const int* __restrict__ src, const int* __restrict__ dst,
                               int* __restrict__ cursor, int* __restrict__ csr_src) {
    int e = blockIdx.x * 256 + threadIdx.x;
    if (e < NE) {
        int p = atomicAdd(&cursor[dst[e]], 1);
        csr_src[p] = src[e];
    }
}

// ---------------- pack weights to bf16, TRANSPOSED: Wbt[n][k] = W[k][n] ----------------
__global__ void pack_w_kernel(const float* __restrict__ Wl1, const float* __restrict__ Wr1,
                              const float* __restrict__ Wl2, const float* __restrict__ Wr2,
                              const float* __restrict__ Wmu, const float* __restrict__ Wlv,
                              const float* __restrict__ bmu, const float* __restrict__ blv,
                              short* __restrict__ Wb1t, short* __restrict__ Wb2t,
                              short* __restrict__ Wb3t, float* __restrict__ bias3) {
    int i = blockIdx.x * 256 + threadIdx.x;
    const int S1 = 512 * 256, S2 = 2 * S1, S3 = S2 + 128 * 256;
    if (i < S1) {
        int c = i >> 8, k = i & 255;
        float v = (c < 256) ? Wl1[k * 256 + c] : Wr1[k * 256 + (c - 256)];
        Wb1t[i] = f2b(v);
    } else if (i < S2) {
        int j = i - S1; int c = j >> 8, k = j & 255;
        float v = (c < 256) ? Wl2[k * 256 + c] : Wr2[k * 256 + (c - 256)];
        Wb2t[j] = f2b(v);
    } else if (i < S3) {
        int j = i - S2; int c = j >> 8, k = j & 255;
        float v = (c < 64) ? Wmu[k * 64 + c] : Wlv[k * 64 + (c - 64)];
        Wb3t[j] = f2b(v);
    } else if (i < S3 + 128) {
        int c = i - S3;
        bias3[c] = (c < 64) ? bmu[c] : blv[c - 64];
    }
}

// ---------------- GEMM: A[M,256] @ W[256,Nc], Wbt[Nc,256] transposed ----------------
// 128-row blocks, no column grid; A frags (2 row-groups) in registers; loop over NCT
// 64-col LDS sub-tiles (32 KB each). ATT=1: fuse a_arr[row][h] for ct<4 (from f32 acc).
template<int A_F32, int OUT_MODE, int NCT, int ATT>
__global__ __launch_bounds__(256) void gemm_k(
    const void* __restrict__ Ap, const short* __restrict__ Wbt,
    void* __restrict__ outp, const float* __restrict__ bias,
    const float* __restrict__ att, float* __restrict__ a_arr, int Nc)
{
    __shared__ short Bs[64 * 256];   // 32 KB, XOR-swizzled chunks (chunk = 8 shorts = 16B)
    const int t = threadIdx.x;
    const int w = t >> 6, lane = t & 63;
    const int row0 = blockIdx.x * 128;
    const int arow = lane & 15, kq = lane >> 4;
    const int xorc = arow & 7;

    // load A fragments once: rows w*32+arow and w*32+16+arow, k-chunks kc*32 + kq*8
    bf16x8 af[2][8];
    {
        int r0 = row0 + w * 32 + arow;      if (r0 > NN - 1) r0 = NN - 1;
        int r1 = row0 + w * 32 + 16 + arow; if (r1 > NN - 1) r1 = NN - 1;
        if (A_F32) {
            const float* A = (const float*)Ap;
            const float* b0 = A + (long)r0 * 256 + kq * 8;
            const float* b1 = A + (long)r1 * 256 + kq * 8;
#pragma unroll
            for (int kc = 0; kc < 8; ++kc) {
                const f32x4* q0 = reinterpret_cast<const f32x4*>(b0 + kc * 32);
                const f32x4* q1 = reinterpret_cast<const f32x4*>(b1 + kc * 32);
                f32x4 u0 = q0[0], u1 = q0[1], v0 = q1[0], v1 = q1[1];
#pragma unroll
                for (int j = 0; j < 4; ++j) {
                    af[0][kc][j] = f2b(u0[j]); af[0][kc][4 + j] = f2b(u1[j]);
                    af[1][kc][j] = f2b(v0[j]); af[1][kc][4 + j] = f2b(v1[j]);
                }
            }
        } else {
            const short* A = (const short*)Ap;
            const short* b0 = A + (long)r0 * 256 + kq * 8;
            const short* b1 = A + (long)r1 * 256 + kq * 8;
#pragma unroll
            for (int kc = 0; kc < 8; ++kc) {
                af[0][kc] = *reinterpret_cast<const bf16x8*>(b0 + kc * 32);
                af[1][kc] = *reinterpret_cast<const bf16x8*>(b1 + kc * 32);
            }
        }
    }

    const int sn = t >> 2;           // staging row 0..63
    const int cq = t & 3;            // 4 threads per row

#pragma unroll 1
    for (int ct = 0; ct < NCT; ++ct) {
        // stage B sub-panel: Bs[n][chunk^(n&7)] = Wbt[ct*64+n][chunk]
        {
            const short* wp = Wbt + (long)(ct * 64 + sn) * 256;
            short* bp = &Bs[sn * 256];
            const int sx = sn & 7;
#pragma unroll
            for (int r = 0; r < 8; ++r) {
                int c = cq + r * 4;      // chunk 0..31
                bf16x8 v = *reinterpret_cast<const bf16x8*>(wp + c * 8);
                *reinterpret_cast<bf16x8*>(bp + ((c ^ sx) * 8)) = v;
            }
        }
        __syncthreads();

        f32x4 acc[2][4];
#pragma unroll
        for (int rb = 0; rb < 2; ++rb)
#pragma unroll
            for (int b = 0; b < 4; ++b) acc[rb][b] = (f32x4){0.f, 0.f, 0.f, 0.f};

#pragma unroll
        for (int kc = 0; kc < 8; ++kc) {
            const int chunk = (kc * 4 + kq) ^ xorc;
#pragma unroll
            for (int nt = 0; nt < 4; ++nt) {
                bf16x8 b = *reinterpret_cast<const bf16x8*>(&Bs[(nt * 16 + arow) * 256 + chunk * 8]);
                acc[0][nt] = __builtin_amdgcn_mfma_f32_16x16x32_bf16(af[0][kc], b, acc[0][nt], 0, 0, 0);
                acc[1][nt] = __builtin_amdgcn_mfma_f32_16x16x32_bf16(af[1][kc], b, acc[1][nt], 0, 0, 0);
            }
        }

        // fused att_pre: ct<4 covers xl head ct (cols ct*64 .. ct*64+63)
        if (ATT && ct < 4) {
            float av[4];
#pragma unroll
            for (int nt = 0; nt < 4; ++nt) av[nt] = att[ct * 64 + nt * 16 + arow];
#pragma unroll
            for (int rb = 0; rb < 2; ++rb)
#pragma unroll
                for (int r = 0; r < 4; ++r) {
                    float pd = av[0] * acc[rb][0][r] + av[1] * acc[rb][1][r]
                             + av[2] * acc[rb][2][r] + av[3] * acc[rb][3][r];
                    pd += SWZF(pd, 0x041F);
                    pd += SWZF(pd, 0x081F);
                    pd += SWZF(pd, 0x101F);
                    pd += SWZF(pd, 0x201F);
                    int grow = row0 + w * 32 + rb * 16 + kq * 4 + r;
                    if (arow == 0 && grow < NN) a_arr[grow * 4 + ct] = pd * C06L2E;
                }
        }

        // write out: C/D layout col = arow, row = kq*4 + r
#pragma unroll
        for (int rb = 0; rb < 2; ++rb)
#pragma unroll
            for (int nt = 0; nt < 4; ++nt) {
                int gcol = ct * 64 + nt * 16 + arow;
#pragma unroll
                for (int r = 0; r < 4; ++r) {
                    int grow = row0 + w * 32 + rb * 16 + kq * 4 + r;
                    if (grow < NN) {
                        float v = acc[rb][nt][r];
                        if (OUT_MODE == 0) {
                            ((short*)outp)[(long)grow * Nc + gcol] = f2b(v);
                        } else {
                            v += bias[gcol];
                            float* o = (float*)outp;
                            if (gcol < 64) o[(long)grow * 64 + gcol] = v;
                            else           o[(long)NN * 64 + (long)grow * 64 + (gcol - 64)] = v;
                        }
                    }
                }
            }
        __syncthreads();   // Bs reads done before next stage
    }
}

// ---------------- fused GATv2 v2 + index prefetch (ds_swizzle reduce — measured fastest) ----------------
// score (log2 domain, dst-constant term dropped): s = a[j][h] + sum_c (0.4*log2e*att_c)*|xl_jc+xr_ic|
__device__ __forceinline__ void edge_abs_score(const short* __restrict__ xlr, int j, int c4,
                                               const float* xr, const f32x4& attv04,
                                               float* xf, float& s) {
    bf16x4 v = *reinterpret_cast<const bf16x4*>(xlr + (long)j * 512 + c4);
    s = 0.f;
#pragma unroll
    for (int k = 0; k < 4; ++k) {
        xf[k] = b2f(v[k]);
        float vv = xf[k] + xr[k];
        s = fmaf(attv04[k], fabsf(vv), s);   // abs = free input modifier
    }
    // 16-lane head-group reduce: xor 1,2,4,8 (DS pipe, overlaps other waves' VALU)
    s += SWZF(s, 0x041F);
    s += SWZF(s, 0x081F);
    s += SWZF(s, 0x101F);
    s += SWZF(s, 0x201F);
}

__global__ __launch_bounds__(256) void gat_node_kernel(
    const short* __restrict__ xlr, const float* __restrict__ aarr,
    const int* __restrict__ offsets, const int* __restrict__ csr_src,
    const float* __restrict__ att, const float* __restrict__ bias,
    const float* __restrict__ ln_g, const float* __restrict__ ln_b,
    short* __restrict__ hout)
{
    const int i = blockIdx.x * 4 + (threadIdx.x >> 6);
    const int lane = threadIdx.x & 63;
    const int h  = lane >> 4;
    const int c4 = h * 64 + (lane & 15) * 4;   // head*64 + 4 channels

    f32x4 attv04 = *reinterpret_cast<const f32x4*>(att + c4);
#pragma unroll
    for (int k = 0; k < 4; ++k) attv04[k] *= C04L2E;

    float xr[4];
    {
        bf16x4 v = *reinterpret_cast<const bf16x4*>(xlr + (long)i * 512 + 256 + c4);
#pragma unroll
        for (int k = 0; k < 4; ++k) xr[k] = b2f(v[k]);
    }

    const int p0 = offsets[i], p1 = offsets[i + 1];

    // prefetch first pass's indices (clamped, branchless)
    int pp = p0 + (lane & 3);
    int jl = csr_src[pp < NE ? pp : NE - 1];

    float m, l;
    float acc[4];
    // self loop first
    {
        float aj = aarr[i * 4 + h];
        float xf[4], s;
        edge_abs_score(xlr, i, c4, xr, attv04, xf, s);
        m = s + aj; l = 1.f;
#pragma unroll
        for (int k = 0; k < 4; ++k) acc[k] = xf[k];
    }

    int p = p0;
    for (; p + 4 <= p1; p += 4) {
        int j0 = __builtin_amdgcn_readlane(jl, 0);
        int j1 = __builtin_amdgcn_readlane(jl, 1);
        int j2 = __builtin_amdgcn_readlane(jl, 2);
        int j3 = __builtin_amdgcn_readlane(jl, 3);
        // prefetch next pass (or tail) indices while this pass computes
        int pn = p + 4 + (lane & 3);
        jl = csr_src[pn < p1 ? pn : (p1 > 0 ? p1 - 1 : 0)];
        float a0 = aarr[j0 * 4 + h], a1 = aarr[j1 * 4 + h];
        float a2 = aarr[j2 * 4 + h], a3 = aarr[j3 * 4 + h];
        float x0[4], x1[4], x2[4], x3[4], s0, s1, s2, s3;
        edge_abs_score(xlr, j0, c4, xr, attv04, x0, s0);
        edge_abs_score(xlr, j1, c4, xr, attv04, x1, s1);
        edge_abs_score(xlr, j2, c4, xr, attv04, x2, s2);
        edge_abs_score(xlr, j3, c4, xr, attv04, x3, s3);
        s0 += a0; s1 += a1; s2 += a2; s3 += a3;
        float sm = fmaxf(fmaxf(s0, s1), fmaxf(s2, s3));
        if (__all(sm <= m + DEFER_THR)) {
            float e0 = __builtin_amdgcn_exp2f(s0 - m);
            float e1 = __builtin_amdgcn_exp2f(s1 - m);
            float e2 = __builtin_amdgcn_exp2f(s2 - m);
            float e3 = __builtin_amdgcn_exp2f(s3 - m);
            l += (e0 + e1) + (e2 + e3);
#pragma unroll
            for (int k = 0; k < 4; ++k)
                acc[k] = fmaf(e0, x0[k], fmaf(e1, x1[k], fmaf(e2, x2[k], fmaf(e3, x3[k], acc[k]))));
        } else {
            float mn = fmaxf(m, sm);
            float corr = __builtin_amdgcn_exp2f(m - mn);
            float e0 = __builtin_amdgcn_exp2f(s0 - mn);
            float e1 = __builtin_amdgcn_exp2f(s1 - mn);
            float e2 = __builtin_amdgcn_exp2f(s2 - mn);
            float e3 = __builtin_amdgcn_exp2f(s3 - mn);
            l = fmaf(l, corr, (e0 + e1) + (e2 + e3));
#pragma unroll
            for (int k = 0; k < 4; ++k)
                acc[k] = fmaf(acc[k], corr,
                         fmaf(e0, x0[k], fmaf(e1, x1[k], fmaf(e2, x2[k], e3 * x3[k]))));
            m = mn;
        }
    }
    // tail 0..3 edges: indices already resident in jl (lanes 0..rem-1)
    int rem = p1 - p;
    for (int tq = 0; tq < rem; ++tq) {
        int j = __builtin_amdgcn_readlane(jl, tq);
        float aj = aarr[j * 4 + h];
        float xa[4], sa;
        edge_abs_score(xlr, j, c4, xr, attv04, xa, sa);
        sa += aj;
        if (__all(sa <= m + DEFER_THR)) {
            float ex = __builtin_amdgcn_exp2f(sa - m);
            l += ex;
#pragma unroll
            for (int k = 0; k < 4; ++k) acc[k] = fmaf(ex, xa[k], acc[k]);
        } else {
            float mn = fmaxf(m, sa);
            float corr = __builtin_amdgcn_exp2f(m - mn);
            float ex = __builtin_amdgcn_exp2f(sa - mn);
            l = fmaf(l, corr, ex);
#pragma unroll
            for (int k = 0; k < 4; ++k) acc[k] = fmaf(acc[k], corr, ex * xa[k]);
            m = mn;
        }
    }

    float inv = 1.f / l;
    f32x4 bv = *reinterpret_cast<const f32x4*>(bias + c4);
    float out[4], s1 = 0.f, s2 = 0.f;
#pragma unroll
    for (int k = 0; k < 4; ++k) {
        out[k] = acc[k] * inv + bv[k];
        s1 += out[k];
        s2 += out[k] * out[k];
    }
    // LN over 256 channels: full-wave butterfly (swizzle xor 1..16, shfl xor 32)
    s1 += SWZF(s1, 0x041F); s2 += SWZF(s2, 0x041F);
    s1 += SWZF(s1, 0x081F); s2 += SWZF(s2, 0x081F);
    s1 += SWZF(s1, 0x101F); s2 += SWZF(s2, 0x101F);
    s1 += SWZF(s1, 0x201F); s2 += SWZF(s2, 0x201F);
    s1 += SWZF(s1, 0x401F); s2 += SWZF(s2, 0x401F);
    s1 += __shfl_xor(s1, 32, 64);
    s2 += __shfl_xor(s2, 32, 64);
    float mu  = s1 * (1.f / 256.f);
    float var = s2 * (1.f / 256.f) - mu * mu;
    float rs  = rsqrtf(var + 1e-5f);
    f32x4 gv  = *reinterpret_cast<const f32x4*>(ln_g + c4);
    f32x4 bbv = *reinterpret_cast<const f32x4*>(ln_b + c4);
    bf16x4 o;
#pragma unroll
    for (int k = 0; k < 4; ++k) {
        float y = (out[k] - mu) * rs * gv[k] + bbv[k];
        y = y > 0.f ? y : expm1f(y);                    // ELU
        o[k] = f2b(y);
    }
    *reinterpret_cast<bf16x4*>(hout + (long)i * 256 + c4) = o;
}

// ---------------- launch ----------------
extern "C" void kernel_launch(void* const* d_in, const int* in_sizes, int n_in,
                              void* d_out, int out_size, void* d_ws, size_t ws_size,
                              hipStream_t stream) {
    const float* x    = (const float*)d_in[0];
    const int*   ei   = (const int*)d_in[1];
    const float* Wl1  = (const float*)d_in[2];
    const float* Wr1  = (const float*)d_in[3];
    const float* att1 = (const float*)d_in[4];
    const float* b1   = (const float*)d_in[5];
    const float* ln1g = (const float*)d_in[6];
    const float* ln1b = (const float*)d_in[7];
    const float* Wl2  = (const float*)d_in[8];
    const float* Wr2  = (const float*)d_in[9];
    const float* att2 = (const float*)d_in[10];
    const float* b2   = (const float*)d_in[11];
    const float* ln2g = (const float*)d_in[12];
    const float* ln2b = (const float*)d_in[13];
    const float* Wmu  = (const float*)d_in[14];
    const float* bmu  = (const float*)d_in[15];
    const float* Wlv  = (const float*)d_in[16];
    const float* blv  = (const float*)d_in[17];

    // workspace layout
    short* bufXL = (short*)d_ws;                       // [N,512] bf16 (xl|xr)
    short* bufH  = bufXL + (long)NN * 512;             // [N,256] bf16 (h)
    short* Wb1t  = bufH + (long)NN * 256;              // 512*256
    short* Wb2t  = Wb1t + 512 * 256;
    short* Wb3t  = Wb2t + 512 * 256;                   // 128*256
    float* bias3 = (float*)(Wb3t + 128 * 256);         // 128
    int* counts  = (int*)(bias3 + 128);
    int* offsets = counts + NN;                        // N+1
    int* cursor  = offsets + NN + 1;
    int* csr_src = cursor + NN;                        // E
    int* blocksum = csr_src + NE;                      // 64
    float* a_arr = (float*)(blocksum + 64);            // [N,4]

    const int* src = ei;
    const int* dst = ei + NE;

    const int NBLK = (NN + 1023) / 1024;               // 49

    // CSR by dst (parallel scan)
    hipMemsetAsync(counts, 0, NN * sizeof(int), stream);
    hist_kernel<<<(NE + 255) / 256, 256, 0, stream>>>(dst, counts);
    scan1_kernel<<<NBLK, 1024, 0, stream>>>(counts, blocksum);
    scan2_kernel<<<1, 64, 0, stream>>>(blocksum, offsets, NBLK);
    scan3_kernel<<<NBLK, 1024, 0, stream>>>(counts, blocksum, offsets, cursor);
    scatter_kernel<<<(NE + 255) / 256, 256, 0, stream>>>(src, dst, cursor, csr_src);

    // pack transposed weights
    pack_w_kernel<<<1153, 256, 0, stream>>>(Wl1, Wr1, Wl2, Wr2, Wmu, Wlv, bmu, blv,
                                            Wb1t, Wb2t, Wb3t, bias3);

    const int GM = (NN + 127) / 128;   // 391 row-blocks

    // layer 1 (A = x in f32, converted in-register; att_pre fused)
    gemm_k<1, 0, 8, 1><<<GM, 256, 0, stream>>>(x, Wb1t, bufXL, nullptr, att1, a_arr, 512);
    gat_node_kernel<<<NN / 4, 256, 0, stream>>>(bufXL, a_arr, offsets, csr_src,
                                                att1, b1, ln1g, ln1b, bufH);
    // layer 2
    gemm_k<0, 0, 8, 1><<<GM, 256, 0, stream>>>(bufH, Wb2t, bufXL, nullptr, att2, a_arr, 512);
    gat_node_kernel<<<NN / 4, 256, 0, stream>>>(bufXL, a_arr, offsets, csr_src,
                                                att2, b2, ln2g, ln2b, bufH);
    // heads: [mu|logvar]
    gemm_k<0, 1, 2, 0><<<GM, 256, 0, stream>>>(bufH, Wb3t, d_out, bias3, nullptr, nullptr, 128);
}

// Round 15
// 326.535 us; speedup vs baseline: 1.3897x; 1.0172x over previous
//
#include <hip/hip_runtime.h>
#include <hip/hip_bf16.h>

#define NN 50000
#define NE 800000
#define HCn 256
#define LATn 64

typedef short bf16x4 __attribute__((ext_vector_type(4)));
typedef short bf16x8 __attribute__((ext_vector_type(8)));
typedef float f32x4 __attribute__((ext_vector_type(4)));

__device__ __forceinline__ short f2b(float f) {
    __hip_bfloat16 h = __float2bfloat16(f);   // RNE
    return __builtin_bit_cast(short, h);
}
__device__ __forceinline__ float b2f(short s) {
    return __bfloat162float(__builtin_bit_cast(__hip_bfloat16, s));
}

// single-instruction lane swizzle (BitMode xor; works within 32-lane halves).
// DS-pipe op: overlaps with other waves' VALU work (measured r8 vs r10: beats DPP).
#define SWZF(v, pat) __builtin_bit_cast(float, __builtin_amdgcn_ds_swizzle(__builtin_bit_cast(int, v), pat))

#define C04L2E 0.5770780163555854f   // 0.4 * log2(e)
#define C06L2E 0.8656170245333781f   // 0.6 * log2(e)
#define DEFER_THR 8.0f               // defer-max threshold (log2 units)

// ---------------- CSR build ----------------
__global__ void hist_kernel(const int* __restrict__ dst, int* __restrict__ counts) {
    int e = blockIdx.x * 256 + threadIdx.x;
    if (e < NE) atomicAdd(&counts[dst[e]], 1);
}

__global__ __launch_bounds__(1024) void scan1_kernel(int* __restrict__ counts,
                                                     int* __restrict__ blocksum) {
    const int g = blockIdx.x * 1024 + threadIdx.x;
    const int lane = threadIdx.x & 63;
    const int wv = threadIdx.x >> 6;            // 0..15
    int v = (g < NN) ? counts[g] : 0;
    int s = v;
#pragma unroll
    for (int d = 1; d < 64; d <<= 1) {
        int t = __shfl_up(s, d, 64);
        if (lane >= d) s += t;
    }
    __shared__ int wsum[16];
    if (lane == 63) wsum[wv] = s;
    __syncthreads();
    if (threadIdx.x == 0) {
        int run = 0;
#pragma unroll
        for (int q = 0; q < 16; ++q) { int t = wsum[q]; wsum[q] = run; run += t; }
        blocksum[blockIdx.x] = run;
    }
    __syncthreads();
    int excl = s - v + wsum[wv];
    if (g < NN) counts[g] = excl;
}

__global__ void scan2_kernel(int* __restrict__ blocksum, int* __restrict__ offsets, int nblk) {
    const int lane = threadIdx.x;               // 64 threads
    int v = (lane < nblk) ? blocksum[lane] : 0;
    int s = v;
#pragma unroll
    for (int d = 1; d < 64; d <<= 1) {
        int t = __shfl_up(s, d, 64);
        if (lane >= d) s += t;
    }
    if (lane < nblk) blocksum[lane] = s - v;    // exclusive
    if (lane == 0) offsets[NN] = NE;
}

__global__ __launch_bounds__(1024) void scan3_kernel(const int* __restrict__ counts,
                                                     const int* __restrict__ blocksum,
                                                     int* __restrict__ offsets,
                                                     int* __restrict__ cursor) {
    const int g = blockIdx.x * 1024 + threadIdx.x;
    if (g < NN) {
        int v = counts[g] + blocksum[blockIdx.x];
        offsets[g] = v;
        cursor[g]  = v;
    }
}

__global__ void scatter_kernel(const int* __restrict__ src, const int* __restrict__ dst,
                               int* __restrict__ cursor, int* __restrict__ csr_src) {
    int e = blockIdx.x * 256 + threadIdx.x;
    if (e < NE) {
        int p = atomicAdd(&cursor[dst[e]], 1);
        csr_src[p] = src[e];
    }
}

// ---------------- pack weights to bf16, TRANSPOSED: Wbt[n][k] = W[k][n] ----------------
__global__ void pack_w_kernel(const float* __restrict__ Wl1, const float* __restrict__ Wr1,
                              const float* __restrict__ Wl2, const float* __restrict__ Wr2,
                              const float* __restrict__ Wmu, const float* __restrict__ Wlv,
                              const float* __restrict__ bmu, const float* __restrict__ blv,
                              short* __restrict__ Wb1t, short* __restrict__ Wb2t,
                              short* __restrict__ Wb3t, float* __restrict__ bias3) {
    int i = blockIdx.x * 256 + threadIdx.x;
    const int S1 = 512 * 256, S2 = 2 * S1, S3 = S2 + 128 * 256;
    if (i < S1) {
        int c = i >> 8, k = i & 255;
        float v = (c < 256) ? Wl1[k * 256 + c] : Wr1[k * 256 + (c - 256)];
        Wb1t[i] = f2b(v);
    } else if (i < S2) {
        int j = i - S1; int c = j >> 8, k = j & 255;
        float v = (c < 256) ? Wl2[k * 256 + c] : Wr2[k * 256 + (c - 256)];
        Wb2t[j] = f2b(v);
    } else if (i < S3) {
        int j = i - S2; int c = j >> 8, k = j & 255;
        float v = (c < 64) ? Wmu[k * 64 + c] : Wlv[k * 64 + (c - 64)];
        Wb3t[j] = f2b(v);
    } else if (i < S3 + 128) {
        int c = i - S3;
        bias3[c] = (c < 64) ? bmu[c] : blv[c - 64];
    }
}

// ---------------- GEMM: A[M,256] @ W[256,Nc], Wbt[Nc,256] transposed ----------------
// 128-row blocks; A frags (2 row-groups) in registers; loop over NCT 64-col LDS sub-tiles.
// OPERAND-SWAPPED MFMA: mfma(b, a) -> lane owns row = lane&15, cols = kq*4 + r (consecutive!)
// => vectorized epilogue stores (bf16x4 / f32x4). ATT=1: fused att_pre (xor16+xor32 reduce).
template<int A_F32, int OUT_MODE, int NCT, int ATT>
__global__ __launch_bounds__(256) void gemm_k(
    const void* __restrict__ Ap, const short* __restrict__ Wbt,
    void* __restrict__ outp, const float* __restrict__ bias,
    const float* __restrict__ att, float* __restrict__ a_arr, int Nc)
{
    __shared__ short Bs[64 * 256];   // 32 KB, XOR-swizzled chunks (chunk = 8 shorts = 16B)
    const int t = threadIdx.x;
    const int w = t >> 6, lane = t & 63;
    const int row0 = blockIdx.x * 128;
    const int arow = lane & 15, kq = lane >> 4;
    const int xorc = arow & 7;

    // load A fragments once: rows w*32+arow and w*32+16+arow, k-chunks kc*32 + kq*8
    bf16x8 af[2][8];
    {
        int r0 = row0 + w * 32 + arow;      if (r0 > NN - 1) r0 = NN - 1;
        int r1 = row0 + w * 32 + 16 + arow; if (r1 > NN - 1) r1 = NN - 1;
        if (A_F32) {
            const float* A = (const float*)Ap;
            const float* b0 = A + (long)r0 * 256 + kq * 8;
            const float* b1 = A + (long)r1 * 256 + kq * 8;
#pragma unroll
            for (int kc = 0; kc < 8; ++kc) {
                const f32x4* q0 = reinterpret_cast<const f32x4*>(b0 + kc * 32);
                const f32x4* q1 = reinterpret_cast<const f32x4*>(b1 + kc * 32);
                f32x4 u0 = q0[0], u1 = q0[1], v0 = q1[0], v1 = q1[1];
#pragma unroll
                for (int j = 0; j < 4; ++j) {
                    af[0][kc][j] = f2b(u0[j]); af[0][kc][4 + j] = f2b(u1[j]);
                    af[1][kc][j] = f2b(v0[j]); af[1][kc][4 + j] = f2b(v1[j]);
                }
            }
        } else {
            const short* A = (const short*)Ap;
            const short* b0 = A + (long)r0 * 256 + kq * 8;
            const short* b1 = A + (long)r1 * 256 + kq * 8;
#pragma unroll
            for (int kc = 0; kc < 8; ++kc) {
                af[0][kc] = *reinterpret_cast<const bf16x8*>(b0 + kc * 32);
                af[1][kc] = *reinterpret_cast<const bf16x8*>(b1 + kc * 32);
            }
        }
    }

    const int sn = t >> 2;           // staging row 0..63
    const int cq = t & 3;            // 4 threads per row

#pragma unroll 1
    for (int ct = 0; ct < NCT; ++ct) {
        // stage B sub-panel: Bs[n][chunk^(n&7)] = Wbt[ct*64+n][chunk]
        {
            const short* wp = Wbt + (long)(ct * 64 + sn) * 256;
            short* bp = &Bs[sn * 256];
            const int sx = sn & 7;
#pragma unroll
            for (int r = 0; r < 8; ++r) {
                int c = cq + r * 4;      // chunk 0..31
                bf16x8 v = *reinterpret_cast<const bf16x8*>(wp + c * 8);
                *reinterpret_cast<bf16x8*>(bp + ((c ^ sx) * 8)) = v;
            }
        }
        __syncthreads();

        f32x4 acc[2][4];
#pragma unroll
        for (int rb = 0; rb < 2; ++rb)
#pragma unroll
            for (int b = 0; b < 4; ++b) acc[rb][b] = (f32x4){0.f, 0.f, 0.f, 0.f};

#pragma unroll
        for (int kc = 0; kc < 8; ++kc) {
            const int chunk = (kc * 4 + kq) ^ xorc;
#pragma unroll
            for (int nt = 0; nt < 4; ++nt) {
                bf16x8 b = *reinterpret_cast<const bf16x8*>(&Bs[(nt * 16 + arow) * 256 + chunk * 8]);
                // swapped operands: D^T layout -> lane row = arow, cols = kq*4 + r
                acc[0][nt] = __builtin_amdgcn_mfma_f32_16x16x32_bf16(b, af[0][kc], acc[0][nt], 0, 0, 0);
                acc[1][nt] = __builtin_amdgcn_mfma_f32_16x16x32_bf16(b, af[1][kc], acc[1][nt], 0, 0, 0);
            }
        }

        // fused att_pre: ct<4 covers xl head ct; lane holds row arow, cols nt*16+kq*4+r
        if (ATT && ct < 4) {
#pragma unroll
            for (int rb = 0; rb < 2; ++rb) {
                float pd = 0.f;
#pragma unroll
                for (int nt = 0; nt < 4; ++nt) {
                    f32x4 avv = *reinterpret_cast<const f32x4*>(att + ct * 64 + nt * 16 + kq * 4);
#pragma unroll
                    for (int r = 0; r < 4; ++r) pd = fmaf(avv[r], acc[rb][nt][r], pd);
                }
                pd += SWZF(pd, 0x401F);          // xor 16 (combine kq 0<->1, 2<->3)
                pd += __shfl_xor(pd, 32, 64);    // xor 32
                int grow = row0 + w * 32 + rb * 16 + arow;
                if (lane < 16 && grow < NN) a_arr[grow * 4 + ct] = pd * C06L2E;
            }
        }

        // write out: lane row = arow, 4 consecutive cols = nt*16 + kq*4 + (0..3)
#pragma unroll
        for (int rb = 0; rb < 2; ++rb) {
            int grow = row0 + w * 32 + rb * 16 + arow;
            if (grow < NN) {
#pragma unroll
                for (int nt = 0; nt < 4; ++nt) {
                    int gc0 = ct * 64 + nt * 16 + kq * 4;
                    if (OUT_MODE == 0) {
                        bf16x4 o;
#pragma unroll
                        for (int r = 0; r < 4; ++r) o[r] = f2b(acc[rb][nt][r]);
                        *reinterpret_cast<bf16x4*>((short*)outp + (long)grow * Nc + gc0) = o;
                    } else {
                        f32x4 bv = *reinterpret_cast<const f32x4*>(bias + gc0);
                        f32x4 o;
#pragma unroll
                        for (int r = 0; r < 4; ++r) o[r] = acc[rb][nt][r] + bv[r];
                        float* ob = (float*)outp;
                        if (gc0 < 64) *reinterpret_cast<f32x4*>(ob + (long)grow * 64 + gc0) = o;
                        else *reinterpret_cast<f32x4*>(ob + (long)NN * 64 + (long)grow * 64 + (gc0 - 64)) = o;
                    }
                }
            }
        }
        __syncthreads();   // Bs reads done before next stage
    }
}

// ---------------- fused GATv2 v2 + index prefetch (ds_swizzle reduce — measured fastest) ----------------
// score (log2 domain, dst-constant term dropped): s = a[j][h] + sum_c (0.4*log2e*att_c)*|xl_jc+xr_ic|
__device__ __forceinline__ void edge_abs_score(const short* __restrict__ xlr, int j, int c4,
                                               const float* xr, const f32x4& attv04,
                                               float* xf, float& s) {
    bf16x4 v = *reinterpret_cast<const bf16x4*>(xlr + (long)j * 512 + c4);
    s = 0.f;
#pragma unroll
    for (int k = 0; k < 4; ++k) {
        xf[k] = b2f(v[k]);
        float vv = xf[k] + xr[k];
        s = fmaf(attv04[k], fabsf(vv), s);   // abs = free input modifier
    }
    // 16-lane head-group reduce: xor 1,2,4,8 (DS pipe, overlaps other waves' VALU)
    s += SWZF(s, 0x041F);
    s += SWZF(s, 0x081F);
    s += SWZF(s, 0x101F);
    s += SWZF(s, 0x201F);
}

__global__ __launch_bounds__(256) void gat_node_kernel(
    const short* __restrict__ xlr, const float* __restrict__ aarr,
    const int* __restrict__ offsets, const int* __restrict__ csr_src,
    const float* __restrict__ att, const float* __restrict__ bias,
    const float* __restrict__ ln_g, const float* __restrict__ ln_b,
    short* __restrict__ hout)
{
    const int i = blockIdx.x * 4 + (threadIdx.x >> 6);
    const int lane = threadIdx.x & 63;
    const int h  = lane >> 4;
    const int c4 = h * 64 + (lane & 15) * 4;   // head*64 + 4 channels

    f32x4 attv04 = *reinterpret_cast<const f32x4*>(att + c4);
#pragma unroll
    for (int k = 0; k < 4; ++k) attv04[k] *= C04L2E;

    float xr[4];
    {
        bf16x4 v = *reinterpret_cast<const bf16x4*>(xlr + (long)i * 512 + 256 + c4);
#pragma unroll
        for (int k = 0; k < 4; ++k) xr[k] = b2f(v[k]);
    }

    const int p0 = offsets[i], p1 = offsets[i + 1];

    // prefetch first pass's indices (clamped, branchless)
    int pp = p0 + (lane & 3);
    int jl = csr_src[pp < NE ? pp : NE - 1];

    float m, l;
    float acc[4];
    // self loop first
    {
        float aj = aarr[i * 4 + h];
        float xf[4], s;
        edge_abs_score(xlr, i, c4, xr, attv04, xf, s);
        m = s + aj; l = 1.f;
#pragma unroll
        for (int k = 0; k < 4; ++k) acc[k] = xf[k];
    }

    int p = p0;
    for (; p + 4 <= p1; p += 4) {
        int j0 = __builtin_amdgcn_readlane(jl, 0);
        int j1 = __builtin_amdgcn_readlane(jl, 1);
        int j2 = __builtin_amdgcn_readlane(jl, 2);
        int j3 = __builtin_amdgcn_readlane(jl, 3);
        // prefetch next pass (or tail) indices while this pass computes
        int pn = p + 4 + (lane & 3);
        jl = csr_src[pn < p1 ? pn : (p1 > 0 ? p1 - 1 : 0)];
        float a0 = aarr[j0 * 4 + h], a1 = aarr[j1 * 4 + h];
        float a2 = aarr[j2 * 4 + h], a3 = aarr[j3 * 4 + h];
        float x0[4], x1[4], x2[4], x3[4], s0, s1, s2, s3;
        edge_abs_score(xlr, j0, c4, xr, attv04, x0, s0);
        edge_abs_score(xlr, j1, c4, xr, attv04, x1, s1);
        edge_abs_score(xlr, j2, c4, xr, attv04, x2, s2);
        edge_abs_score(xlr, j3, c4, xr, attv04, x3, s3);
        s0 += a0; s1 += a1; s2 += a2; s3 += a3;
        float sm = fmaxf(fmaxf(s0, s1), fmaxf(s2, s3));
        if (__all(sm <= m + DEFER_THR)) {
            float e0 = __builtin_amdgcn_exp2f(s0 - m);
            float e1 = __builtin_amdgcn_exp2f(s1 - m);
            float e2 = __builtin_amdgcn_exp2f(s2 - m);
            float e3 = __builtin_amdgcn_exp2f(s3 - m);
            l += (e0 + e1) + (e2 + e3);
#pragma unroll
            for (int k = 0; k < 4; ++k)
                acc[k] = fmaf(e0, x0[k], fmaf(e1, x1[k], fmaf(e2, x2[k], fmaf(e3, x3[k], acc[k]))));
        } else {
            float mn = fmaxf(m, sm);
            float corr = __builtin_amdgcn_exp2f(m - mn);
            float e0 = __builtin_amdgcn_exp2f(s0 - mn);
            float e1 = __builtin_amdgcn_exp2f(s1 - mn);
            float e2 = __builtin_amdgcn_exp2f(s2 - mn);
            float e3 = __builtin_amdgcn_exp2f(s3 - mn);
            l = fmaf(l, corr, (e0 + e1) + (e2 + e3));
#pragma unroll
            for (int k = 0; k < 4; ++k)
                acc[k] = fmaf(acc[k], corr,
                         fmaf(e0, x0[k], fmaf(e1, x1[k], fmaf(e2, x2[k], e3 * x3[k]))));
            m = mn;
        }
    }
    // tail 0..3 edges: indices already resident in jl (lanes 0..rem-1)
    int rem = p1 - p;
    for (int tq = 0; tq < rem; ++tq) {
        int j = __builtin_amdgcn_readlane(jl, tq);
        float aj = aarr[j * 4 + h];
        float xa[4], sa;
        edge_abs_score(xlr, j, c4, xr, attv04, xa, sa);
        sa += aj;
        if (__all(sa <= m + DEFER_THR)) {
            float ex = __builtin_amdgcn_exp2f(sa - m);
            l += ex;
#pragma unroll
            for (int k = 0; k < 4; ++k) acc[k] = fmaf(ex, xa[k], acc[k]);
        } else {
            float mn = fmaxf(m, sa);
            float corr = __builtin_amdgcn_exp2f(m - mn);
            float ex = __builtin_amdgcn_exp2f(sa - mn);
            l = fmaf(l, corr, ex);
#pragma unroll
            for (int k = 0; k < 4; ++k) acc[k] = fmaf(acc[k], corr, ex * xa[k]);
            m = mn;
        }
    }

    float inv = 1.f / l;
    f32x4 bv = *reinterpret_cast<const f32x4*>(bias + c4);
    float out[4], s1 = 0.f, s2 = 0.f;
#pragma unroll
    for (int k = 0; k < 4; ++k) {
        out[k] = acc[k] * inv + bv[k];
        s1 += out[k];
        s2 += out[k] * out[k];
    }
    // LN over 256 channels: full-wave butterfly (swizzle xor 1..16, shfl xor 32)
    s1 += SWZF(s1, 0x041F); s2 += SWZF(s2, 0x041F);
    s1 += SWZF(s1, 0x081F); s2 += SWZF(s2, 0x081F);
    s1 += SWZF(s1, 0x101F); s2 += SWZF(s2, 0x101F);
    s1 += SWZF(s1, 0x201F); s2 += SWZF(s2, 0x201F);
    s1 += SWZF(s1, 0x401F); s2 += SWZF(s2, 0x401F);
    s1 += __shfl_xor(s1, 32, 64);
    s2 += __shfl_xor(s2, 32, 64);
    float mu  = s1 * (1.f / 256.f);
    float var = s2 * (1.f / 256.f) - mu * mu;
    float rs  = rsqrtf(var + 1e-5f);
    f32x4 gv  = *reinterpret_cast<const f32x4*>(ln_g + c4);
    f32x4 bbv = *reinterpret_cast<const f32x4*>(ln_b + c4);
    bf16x4 o;
#pragma unroll
    for (int k = 0; k < 4; ++k) {
        float y = (out[k] - mu) * rs * gv[k] + bbv[k];
        y = y > 0.f ? y : expm1f(y);                    // ELU
        o[k] = f2b(y);
    }
    *reinterpret_cast<bf16x4*>(hout + (long)i * 256 + c4) = o;
}

// ---------------- launch ----------------
extern "C" void kernel_launch(void* const* d_in, const int* in_sizes, int n_in,
                              void* d_out, int out_size, void* d_ws, size_t ws_size,
                              hipStream_t stream) {
    const float* x    = (const float*)d_in[0];
    const int*   ei   = (const int*)d_in[1];
    const float* Wl1  = (const float*)d_in[2];
    const float* Wr1  = (const float*)d_in[3];
    const float* att1 = (const float*)d_in[4];
    const float* b1   = (const float*)d_in[5];
    const float* ln1g = (const float*)d_in[6];
    const float* ln1b = (const float*)d_in[7];
    const float* Wl2  = (const float*)d_in[8];
    const float* Wr2  = (const float*)d_in[9];
    const float* att2 = (const float*)d_in[10];
    const float* b2   = (const float*)d_in[11];
    const float* ln2g = (const float*)d_in[12];
    const float* ln2b = (const float*)d_in[13];
    const float* Wmu  = (const float*)d_in[14];
    const float* bmu  = (const float*)d_in[15];
    const float* Wlv  = (const float*)d_in[16];
    const float* blv  = (const float*)d_in[17];

    // workspace layout
    short* bufXL = (short*)d_ws;                       // [N,512] bf16 (xl|xr)
    short* bufH  = bufXL + (long)NN * 512;             // [N,256] bf16 (h)
    short* Wb1t  = bufH + (long)NN * 256;              // 512*256
    short* Wb2t  = Wb1t + 512 * 256;
    short* Wb3t  = Wb2t + 512 * 256;                   // 128*256
    float* bias3 = (float*)(Wb3t + 128 * 256);         // 128
    int* counts  = (int*)(bias3 + 128);
    int* offsets = counts + NN;                        // N+1
    int* cursor  = offsets + NN + 1;
    int* csr_src = cursor + NN;                        // E
    int* blocksum = csr_src + NE;                      // 64
    float* a_arr = (float*)(blocksum + 64);            // [N,4]

    const int* src = ei;
    const int* dst = ei + NE;

    const int NBLK = (NN + 1023) / 1024;               // 49

    // CSR by dst (parallel scan)
    hipMemsetAsync(counts, 0, NN * sizeof(int), stream);
    hist_kernel<<<(NE + 255) / 256, 256, 0, stream>>>(dst, counts);
    scan1_kernel<<<NBLK, 1024, 0, stream>>>(counts, blocksum);
    scan2_kernel<<<1, 64, 0, stream>>>(blocksum, offsets, NBLK);
    scan3_kernel<<<NBLK, 1024, 0, stream>>>(counts, blocksum, offsets, cursor);
    scatter_kernel<<<(NE + 255) / 256, 256, 0, stream>>>(src, dst, cursor, csr_src);

    // pack transposed weights
    pack_w_kernel<<<1153, 256, 0, stream>>>(Wl1, Wr1, Wl2, Wr2, Wmu, Wlv, bmu, blv,
                                            Wb1t, Wb2t, Wb3t, bias3);

    const int GM = (NN + 127) / 128;   // 391 row-blocks

    // layer 1 (A = x in f32, converted in-register; att_pre fused)
    gemm_k<1, 0, 8, 1><<<GM, 256, 0, stream>>>(x, Wb1t, bufXL, nullptr, att1, a_arr, 512);
    gat_node_kernel<<<NN / 4, 256, 0, stream>>>(bufXL, a_arr, offsets, csr_src,
                                                att1, b1, ln1g, ln1b, bufH);
    // layer 2
    gemm_k<0, 0, 8, 1><<<GM, 256, 0, stream>>>(bufH, Wb2t, bufXL, nullptr, att2, a_arr, 512);
    gat_node_kernel<<<NN / 4, 256, 0, stream>>>(bufXL, a_arr, offsets, csr_src,
                                                att2, b2, ln2g, ln2b, bufH);
    // heads: [mu|logvar]
    gemm_k<0, 1, 2, 0><<<GM, 256, 0, stream>>>(bufH, Wb3t, d_out, bias3, nullptr, nullptr, 128);
}

// Round 16
// 324.787 us; speedup vs baseline: 1.3971x; 1.0054x over previous
//
#include <hip/hip_runtime.h>
#include <hip/hip_bf16.h>

#define NN 50000
#define NE 800000
#define HCn 256
#define LATn 64

typedef short bf16x4 __attribute__((ext_vector_type(4)));
typedef short bf16x8 __attribute__((ext_vector_type(8)));
typedef float f32x4 __attribute__((ext_vector_type(4)));

__device__ __forceinline__ short f2b(float f) {
    __hip_bfloat16 h = __float2bfloat16(f);   // RNE
    return __builtin_bit_cast(short, h);
}
__device__ __forceinline__ float b2f(short s) {
    return __bfloat162float(__builtin_bit_cast(__hip_bfloat16, s));
}

// single-instruction lane swizzle (BitMode xor; works within 32-lane halves).
// DS-pipe op: overlaps with other waves' VALU work (measured r8 vs r10: beats DPP).
#define SWZF(v, pat) __builtin_bit_cast(float, __builtin_amdgcn_ds_swizzle(__builtin_bit_cast(int, v), pat))

#define C04L2E 0.5770780163555854f   // 0.4 * log2(e)
#define C06L2E 0.8656170245333781f   // 0.6 * log2(e)
#define DEFER_THR 8.0f               // defer-max threshold (log2 units)

// ---------------- CSR build ----------------
__global__ void hist_kernel(const int* __restrict__ dst, int* __restrict__ counts) {
    int e = blockIdx.x * 256 + threadIdx.x;
    if (e < NE) atomicAdd(&counts[dst[e]], 1);
}

__global__ __launch_bounds__(1024) void scan1_kernel(int* __restrict__ counts,
                                                     int* __restrict__ blocksum) {
    const int g = blockIdx.x * 1024 + threadIdx.x;
    const int lane = threadIdx.x & 63;
    const int wv = threadIdx.x >> 6;            // 0..15
    int v = (g < NN) ? counts[g] : 0;
    int s = v;
#pragma unroll
    for (int d = 1; d < 64; d <<= 1) {
        int t = __shfl_up(s, d, 64);
        if (lane >= d) s += t;
    }
    __shared__ int wsum[16];
    if (lane == 63) wsum[wv] = s;
    __syncthreads();
    if (threadIdx.x == 0) {
        int run = 0;
#pragma unroll
        for (int q = 0; q < 16; ++q) { int t = wsum[q]; wsum[q] = run; run += t; }
        blocksum[blockIdx.x] = run;
    }
    __syncthreads();
    int excl = s - v + wsum[wv];
    if (g < NN) counts[g] = excl;
}

// scan3 with folded block-base computation: each block sums blocksum[0..blockIdx-1]
// via a masked 64-lane reduce (nblk = 49 <= 64). Also writes offsets[NN] = NE.
__global__ __launch_bounds__(1024) void scan3_kernel(const int* __restrict__ counts,
                                                     const int* __restrict__ blocksum,
                                                     int* __restrict__ offsets,
                                                     int* __restrict__ cursor) {
    const int lane = threadIdx.x & 63;
    int v = (lane < blockIdx.x) ? blocksum[lane] : 0;
#pragma unroll
    for (int d = 32; d; d >>= 1) v += __shfl_xor(v, d, 64);
    const int g = blockIdx.x * 1024 + threadIdx.x;
    if (g < NN) {
        int o = counts[g] + v;
        offsets[g] = o;
        cursor[g]  = o;
    }
    if (blockIdx.x == 0 && threadIdx.x == 0) offsets[NN] = NE;
}

__global__ void scatter_kernel(const int* __restrict__ src, const int* __restrict__ dst,
                               int* __restrict__ cursor, int* __restrict__ csr_src) {
    int e = blockIdx.x * 256 + threadIdx.x;
    if (e < NE) {
        int p = atomicAdd(&cursor[dst[e]], 1);
        csr_src[p] = src[e];
    }
}

// ---------------- pack weights to bf16, TRANSPOSED: Wbt[n][k] = W[k][n] ----------------
__global__ void pack_w_kernel(const float* __restrict__ Wl1, const float* __restrict__ Wr1,
                              const float* __restrict__ Wl2, const float* __restrict__ Wr2,
                              const float* __restrict__ Wmu, const float* __restrict__ Wlv,
                              const float* __restrict__ bmu, const float* __restrict__ blv,
                              short* __restrict__ Wb1t, short* __restrict__ Wb2t,
                              short* __restrict__ Wb3t, float* __restrict__ bias3) {
    int i = blockIdx.x * 256 + threadIdx.x;
    const int S1 = 512 * 256, S2 = 2 * S1, S3 = S2 + 128 * 256;
    if (i < S1) {
        int c = i >> 8, k = i & 255;
        float v = (c < 256) ? Wl1[k * 256 + c] : Wr1[k * 256 + (c - 256)];
        Wb1t[i] = f2b(v);
    } else if (i < S2) {
        int j = i - S1; int c = j >> 8, k = j & 255;
        float v = (c < 256) ? Wl2[k * 256 + c] : Wr2[k * 256 + (c - 256)];
        Wb2t[j] = f2b(v);
    } else if (i < S3) {
        int j = i - S2; int c = j >> 8, k = j & 255;
        float v = (c < 64) ? Wmu[k * 64 + c] : Wlv[k * 64 + (c - 64)];
        Wb3t[j] = f2b(v);
    } else if (i < S3 + 128) {
        int c = i - S3;
        bias3[c] = (c < 64) ? bmu[c] : blv[c - 64];
    }
}

// ---------------- GEMM: A[M,256] @ W[256,Nc], Wbt[Nc,256] transposed ----------------
// 128-row blocks; A frags (2 row-groups) in registers; loop over NCT 64-col LDS sub-tiles.
// Register double-buffered B staging (T14): next ct's panel loads issue right after the
// barrier and drain under the 64 MFMAs; vmcnt waits land at the next LDS write.
// OPERAND-SWAPPED MFMA: mfma(b, a) -> lane owns row = lane&15, cols = kq*4 + r.
template<int A_F32, int OUT_MODE, int NCT, int ATT>
__global__ __launch_bounds__(256) void gemm_k(
    const void* __restrict__ Ap, const short* __restrict__ Wbt,
    void* __restrict__ outp, const float* __restrict__ bias,
    const float* __restrict__ att, float* __restrict__ a_arr, int Nc)
{
    __shared__ short Bs[64 * 256];   // 32 KB, XOR-swizzled chunks (chunk = 8 shorts = 16B)
    const int t = threadIdx.x;
    const int w = t >> 6, lane = t & 63;
    const int row0 = blockIdx.x * 128;
    const int arow = lane & 15, kq = lane >> 4;
    const int xorc = arow & 7;

    // load A fragments once: rows w*32+arow and w*32+16+arow, k-chunks kc*32 + kq*8
    bf16x8 af[2][8];
    {
        int r0 = row0 + w * 32 + arow;      if (r0 > NN - 1) r0 = NN - 1;
        int r1 = row0 + w * 32 + 16 + arow; if (r1 > NN - 1) r1 = NN - 1;
        if (A_F32) {
            const float* A = (const float*)Ap;
            const float* b0 = A + (long)r0 * 256 + kq * 8;
            const float* b1 = A + (long)r1 * 256 + kq * 8;
#pragma unroll
            for (int kc = 0; kc < 8; ++kc) {
                const f32x4* q0 = reinterpret_cast<const f32x4*>(b0 + kc * 32);
                const f32x4* q1 = reinterpret_cast<const f32x4*>(b1 + kc * 32);
                f32x4 u0 = q0[0], u1 = q0[1], v0 = q1[0], v1 = q1[1];
#pragma unroll
                for (int j = 0; j < 4; ++j) {
                    af[0][kc][j] = f2b(u0[j]); af[0][kc][4 + j] = f2b(u1[j]);
                    af[1][kc][j] = f2b(v0[j]); af[1][kc][4 + j] = f2b(v1[j]);
                }
            }
        } else {
            const short* A = (const short*)Ap;
            const short* b0 = A + (long)r0 * 256 + kq * 8;
            const short* b1 = A + (long)r1 * 256 + kq * 8;
#pragma unroll
            for (int kc = 0; kc < 8; ++kc) {
                af[0][kc] = *reinterpret_cast<const bf16x8*>(b0 + kc * 32);
                af[1][kc] = *reinterpret_cast<const bf16x8*>(b1 + kc * 32);
            }
        }
    }

    const int sn = t >> 2;           // staging row 0..63
    const int cq = t & 3;            // 4 threads per row
    const int sx = sn & 7;
    short* bp = &Bs[sn * 256];

    // prologue: load ct=0 B sub-panel into registers
    bf16x8 breg[8];
    {
        const short* wp = Wbt + (long)sn * 256;
#pragma unroll
        for (int r = 0; r < 8; ++r)
            breg[r] = *reinterpret_cast<const bf16x8*>(wp + (cq + r * 4) * 8);
    }

#pragma unroll 1
    for (int ct = 0; ct < NCT; ++ct) {
        // write staged regs to LDS (swizzled)
#pragma unroll
        for (int r = 0; r < 8; ++r) {
            int c = cq + r * 4;
            *reinterpret_cast<bf16x8*>(bp + ((c ^ sx) * 8)) = breg[r];
        }
        __syncthreads();

        // prefetch next ct's panel (latency hides under MFMAs below)
        if (ct + 1 < NCT) {
            const short* wp = Wbt + (long)((ct + 1) * 64 + sn) * 256;
#pragma unroll
            for (int r = 0; r < 8; ++r)
                breg[r] = *reinterpret_cast<const bf16x8*>(wp + (cq + r * 4) * 8);
        }

        f32x4 acc[2][4];
#pragma unroll
        for (int rb = 0; rb < 2; ++rb)
#pragma unroll
            for (int b = 0; b < 4; ++b) acc[rb][b] = (f32x4){0.f, 0.f, 0.f, 0.f};

#pragma unroll
        for (int kc = 0; kc < 8; ++kc) {
            const int chunk = (kc * 4 + kq) ^ xorc;
#pragma unroll
            for (int nt = 0; nt < 4; ++nt) {
                bf16x8 b = *reinterpret_cast<const bf16x8*>(&Bs[(nt * 16 + arow) * 256 + chunk * 8]);
                // swapped operands: D^T layout -> lane row = arow, cols = kq*4 + r
                acc[0][nt] = __builtin_amdgcn_mfma_f32_16x16x32_bf16(b, af[0][kc], acc[0][nt], 0, 0, 0);
                acc[1][nt] = __builtin_amdgcn_mfma_f32_16x16x32_bf16(b, af[1][kc], acc[1][nt], 0, 0, 0);
            }
        }

        // fused att_pre: ct<4 covers xl head ct; lane holds row arow, cols nt*16+kq*4+r
        if (ATT && ct < 4) {
#pragma unroll
            for (int rb = 0; rb < 2; ++rb) {
                float pd = 0.f;
#pragma unroll
                for (int nt = 0; nt < 4; ++nt) {
                    f32x4 avv = *reinterpret_cast<const f32x4*>(att + ct * 64 + nt * 16 + kq * 4);
#pragma unroll
                    for (int r = 0; r < 4; ++r) pd = fmaf(avv[r], acc[rb][nt][r], pd);
                }
                pd += SWZF(pd, 0x401F);          // xor 16 (combine kq 0<->1, 2<->3)
                pd += __shfl_xor(pd, 32, 64);    // xor 32
                int grow = row0 + w * 32 + rb * 16 + arow;
                if (lane < 16 && grow < NN) a_arr[grow * 4 + ct] = pd * C06L2E;
            }
        }

        // write out: lane row = arow, 4 consecutive cols = nt*16 + kq*4 + (0..3)
#pragma unroll
        for (int rb = 0; rb < 2; ++rb) {
            int grow = row0 + w * 32 + rb * 16 + arow;
            if (grow < NN) {
#pragma unroll
                for (int nt = 0; nt < 4; ++nt) {
                    int gc0 = ct * 64 + nt * 16 + kq * 4;
                    if (OUT_MODE == 0) {
                        bf16x4 o;
#pragma unroll
                        for (int r = 0; r < 4; ++r) o[r] = f2b(acc[rb][nt][r]);
                        *reinterpret_cast<bf16x4*>((short*)outp + (long)grow * Nc + gc0) = o;
                    } else {
                        f32x4 bv = *reinterpret_cast<const f32x4*>(bias + gc0);
                        f32x4 o;
#pragma unroll
                        for (int r = 0; r < 4; ++r) o[r] = acc[rb][nt][r] + bv[r];
                        float* ob = (float*)outp;
                        if (gc0 < 64) *reinterpret_cast<f32x4*>(ob + (long)grow * 64 + gc0) = o;
                        else *reinterpret_cast<f32x4*>(ob + (long)NN * 64 + (long)grow * 64 + (gc0 - 64)) = o;
                    }
                }
            }
        }
        __syncthreads();   // Bs reads done before next stage write
    }
}

// ---------------- fused GATv2 v2 + index prefetch (ds_swizzle reduce — measured fastest) ----------------
// score (log2 domain, dst-constant term dropped): s = a[j][h] + sum_c (0.4*log2e*att_c)*|xl_jc+xr_ic|
__device__ __forceinline__ void edge_abs_score(const short* __restrict__ xlr, int j, int c4,
                                               const float* xr, const f32x4& attv04,
                                               float* xf, float& s) {
    bf16x4 v = *reinterpret_cast<const bf16x4*>(xlr + (long)j * 512 + c4);
    s = 0.f;
#pragma unroll
    for (int k = 0; k < 4; ++k) {
        xf[k] = b2f(v[k]);
        float vv = xf[k] + xr[k];
        s = fmaf(attv04[k], fabsf(vv), s);   // abs = free input modifier
    }
    // 16-lane head-group reduce: xor 1,2,4,8 (DS pipe, overlaps other waves' VALU)
    s += SWZF(s, 0x041F);
    s += SWZF(s, 0x081F);
    s += SWZF(s, 0x101F);
    s += SWZF(s, 0x201F);
}

__global__ __launch_bounds__(256) void gat_node_kernel(
    const short* __restrict__ xlr, const float* __restrict__ aarr,
    const int* __restrict__ offsets, const int* __restrict__ csr_src,
    const float* __restrict__ att, const float* __restrict__ bias,
    const float* __restrict__ ln_g, const float* __restrict__ ln_b,
    short* __restrict__ hout)
{
    const int i = blockIdx.x * 4 + (threadIdx.x >> 6);
    const int lane = threadIdx.x & 63;
    const int h  = lane >> 4;
    const int c4 = h * 64 + (lane & 15) * 4;   // head*64 + 4 channels

    f32x4 attv04 = *reinterpret_cast<const f32x4*>(att + c4);
#pragma unroll
    for (int k = 0; k < 4; ++k) attv04[k] *= C04L2E;

    float xr[4];
    {
        bf16x4 v = *reinterpret_cast<const bf16x4*>(xlr + (long)i * 512 + 256 + c4);
#pragma unroll
        for (int k = 0; k < 4; ++k) xr[k] = b2f(v[k]);
    }

    const int p0 = offsets[i], p1 = offsets[i + 1];

    // prefetch first pass's indices (clamped, branchless)
    int pp = p0 + (lane & 3);
    int jl = csr_src[pp < NE ? pp : NE - 1];

    float m, l;
    float acc[4];
    // self loop first
    {
        float aj = aarr[i * 4 + h];
        float xf[4], s;
        edge_abs_score(xlr, i, c4, xr, attv04, xf, s);
        m = s + aj; l = 1.f;
#pragma unroll
        for (int k = 0; k < 4; ++k) acc[k] = xf[k];
    }

    int p = p0;
    for (; p + 4 <= p1; p += 4) {
        int j0 = __builtin_amdgcn_readlane(jl, 0);
        int j1 = __builtin_amdgcn_readlane(jl, 1);
        int j2 = __builtin_amdgcn_readlane(jl, 2);
        int j3 = __builtin_amdgcn_readlane(jl, 3);
        // prefetch next pass (or tail) indices while this pass computes
        int pn = p + 4 + (lane & 3);
        jl = csr_src[pn < p1 ? pn : (p1 > 0 ? p1 - 1 : 0)];
        float a0 = aarr[j0 * 4 + h], a1 = aarr[j1 * 4 + h];
        float a2 = aarr[j2 * 4 + h], a3 = aarr[j3 * 4 + h];
        float x0[4], x1[4], x2[4], x3[4], s0, s1, s2, s3;
        edge_abs_score(xlr, j0, c4, xr, attv04, x0, s0);
        edge_abs_score(xlr, j1, c4, xr, attv04, x1, s1);
        edge_abs_score(xlr, j2, c4, xr, attv04, x2, s2);
        edge_abs_score(xlr, j3, c4, xr, attv04, x3, s3);
        s0 += a0; s1 += a1; s2 += a2; s3 += a3;
        float sm = fmaxf(fmaxf(s0, s1), fmaxf(s2, s3));
        if (__all(sm <= m + DEFER_THR)) {
            float e0 = __builtin_amdgcn_exp2f(s0 - m);
            float e1 = __builtin_amdgcn_exp2f(s1 - m);
            float e2 = __builtin_amdgcn_exp2f(s2 - m);
            float e3 = __builtin_amdgcn_exp2f(s3 - m);
            l += (e0 + e1) + (e2 + e3);
#pragma unroll
            for (int k = 0; k < 4; ++k)
                acc[k] = fmaf(e0, x0[k], fmaf(e1, x1[k], fmaf(e2, x2[k], fmaf(e3, x3[k], acc[k]))));
        } else {
            float mn = fmaxf(m, sm);
            float corr = __builtin_amdgcn_exp2f(m - mn);
            float e0 = __builtin_amdgcn_exp2f(s0 - mn);
            float e1 = __builtin_amdgcn_exp2f(s1 - mn);
            float e2 = __builtin_amdgcn_exp2f(s2 - mn);
            float e3 = __builtin_amdgcn_exp2f(s3 - mn);
            l = fmaf(l, corr, (e0 + e1) + (e2 + e3));
#pragma unroll
            for (int k = 0; k < 4; ++k)
                acc[k] = fmaf(acc[k], corr,
                         fmaf(e0, x0[k], fmaf(e1, x1[k], fmaf(e2, x2[k], e3 * x3[k]))));
            m = mn;
        }
    }
    // tail 0..3 edges: indices already resident in jl (lanes 0..rem-1)
    int rem = p1 - p;
    for (int tq = 0; tq < rem; ++tq) {
        int j = __builtin_amdgcn_readlane(jl, tq);
        float aj = aarr[j * 4 + h];
        float xa[4], sa;
        edge_abs_score(xlr, j, c4, xr, attv04, xa, sa);
        sa += aj;
        if (__all(sa <= m + DEFER_THR)) {
            float ex = __builtin_amdgcn_exp2f(sa - m);
            l += ex;
#pragma unroll
            for (int k = 0; k < 4; ++k) acc[k] = fmaf(ex, xa[k], acc[k]);
        } else {
            float mn = fmaxf(m, sa);
            float corr = __builtin_amdgcn_exp2f(m - mn);
            float ex = __builtin_amdgcn_exp2f(sa - mn);
            l = fmaf(l, corr, ex);
#pragma unroll
            for (int k = 0; k < 4; ++k) acc[k] = fmaf(acc[k], corr, ex * xa[k]);
            m = mn;
        }
    }

    float inv = 1.f / l;
    f32x4 bv = *reinterpret_cast<const f32x4*>(bias + c4);
    float out[4], s1 = 0.f, s2 = 0.f;
#pragma unroll
    for (int k = 0; k < 4; ++k) {
        out[k] = acc[k] * inv + bv[k];
        s1 += out[k];
        s2 += out[k] * out[k];
    }
    // LN over 256 channels: full-wave butterfly (swizzle xor 1..16, shfl xor 32)
    s1 += SWZF(s1, 0x041F); s2 += SWZF(s2, 0x041F);
    s1 += SWZF(s1, 0x081F); s2 += SWZF(s2, 0x081F);
    s1 += SWZF(s1, 0x101F); s2 += SWZF(s2, 0x101F);
    s1 += SWZF(s1, 0x201F); s2 += SWZF(s2, 0x201F);
    s1 += SWZF(s1, 0x401F); s2 += SWZF(s2, 0x401F);
    s1 += __shfl_xor(s1, 32, 64);
    s2 += __shfl_xor(s2, 32, 64);
    float mu  = s1 * (1.f / 256.f);
    float var = s2 * (1.f / 256.f) - mu * mu;
    float rs  = rsqrtf(var + 1e-5f);
    f32x4 gv  = *reinterpret_cast<const f32x4*>(ln_g + c4);
    f32x4 bbv = *reinterpret_cast<const f32x4*>(ln_b + c4);
    bf16x4 o;
#pragma unroll
    for (int k = 0; k < 4; ++k) {
        float y = (out[k] - mu) * rs * gv[k] + bbv[k];
        y = y > 0.f ? y : expm1f(y);                    // ELU
        o[k] = f2b(y);
    }
    *reinterpret_cast<bf16x4*>(hout + (long)i * 256 + c4) = o;
}

// ---------------- launch ----------------
extern "C" void kernel_launch(void* const* d_in, const int* in_sizes, int n_in,
                              void* d_out, int out_size, void* d_ws, size_t ws_size,
                              hipStream_t stream) {
    const float* x    = (const float*)d_in[0];
    const int*   ei   = (const int*)d_in[1];
    const float* Wl1  = (const float*)d_in[2];
    const float* Wr1  = (const float*)d_in[3];
    const float* att1 = (const float*)d_in[4];
    const float* b1   = (const float*)d_in[5];
    const float* ln1g = (const float*)d_in[6];
    const float* ln1b = (const float*)d_in[7];
    const float* Wl2  = (const float*)d_in[8];
    const float* Wr2  = (const float*)d_in[9];
    const float* att2 = (const float*)d_in[10];
    const float* b2   = (const float*)d_in[11];
    const float* ln2g = (const float*)d_in[12];
    const float* ln2b = (const float*)d_in[13];
    const float* Wmu  = (const float*)d_in[14];
    const float* bmu  = (const float*)d_in[15];
    const float* Wlv  = (const float*)d_in[16];
    const float* blv  = (const float*)d_in[17];

    // workspace layout
    short* bufXL = (short*)d_ws;                       // [N,512] bf16 (xl|xr)
    short* bufH  = bufXL + (long)NN * 512;             // [N,256] bf16 (h)
    short* Wb1t  = bufH + (long)NN * 256;              // 512*256
    short* Wb2t  = Wb1t + 512 * 256;
    short* Wb3t  = Wb2t + 512 * 256;                   // 128*256
    float* bias3 = (float*)(Wb3t + 128 * 256);         // 128
    int* counts  = (int*)(bias3 + 128);
    int* offsets = counts + NN;                        // N+1
    int* cursor  = offsets + NN + 1;
    int* csr_src = cursor + NN;                        // E
    int* blocksum = csr_src + NE;                      // 64
    float* a_arr = (float*)(blocksum + 64);            // [N,4]

    const int* src = ei;
    const int* dst = ei + NE;

    const int NBLK = (NN + 1023) / 1024;               // 49

    // CSR by dst (parallel scan; scan2 folded into scan3)
    hipMemsetAsync(counts, 0, NN * sizeof(int), stream);
    hist_kernel<<<(NE + 255) / 256, 256, 0, stream>>>(dst, counts);
    scan1_kernel<<<NBLK, 1024, 0, stream>>>(counts, blocksum);
    scan3_kernel<<<NBLK, 1024, 0, stream>>>(counts, blocksum, offsets, cursor);
    scatter_kernel<<<(NE + 255) / 256, 256, 0, stream>>>(src, dst, cursor, csr_src);

    // pack transposed weights
    pack_w_kernel<<<1153, 256, 0, stream>>>(Wl1, Wr1, Wl2, Wr2, Wmu, Wlv, bmu, blv,
                                            Wb1t, Wb2t, Wb3t, bias3);

    const int GM = (NN + 127) / 128;   // 391 row-blocks

    // layer 1 (A = x in f32, converted in-register; att_pre fused)
    gemm_k<1, 0, 8, 1><<<GM, 256, 0, stream>>>(x, Wb1t, bufXL, nullptr, att1, a_arr, 512);
    gat_node_kernel<<<NN / 4, 256, 0, stream>>>(bufXL, a_arr, offsets, csr_src,
                                                att1, b1, ln1g, ln1b, bufH);
    // layer 2
    gemm_k<0, 0, 8, 1><<<GM, 256, 0, stream>>>(bufH, Wb2t, bufXL, nullptr, att2, a_arr, 512);
    gat_node_kernel<<<NN / 4, 256, 0, stream>>>(bufXL, a_arr, offsets, csr_src,
                                                att2, b2, ln2g, ln2b, bufH);
    // heads: [mu|logvar]
    gemm_k<0, 1, 2, 0><<<GM, 256, 0, stream>>>(bufH, Wb3t, d_out, bias3, nullptr, nullptr, 128);
}

// Round 17
// 319.950 us; speedup vs baseline: 1.4183x; 1.0151x over previous
//
#include <hip/hip_runtime.h>
#include <hip/hip_bf16.h>

#define NN 50000
#define NE 800000
#define HCn 256
#define LATn 64

typedef short bf16x4 __attribute__((ext_vector_type(4)));
typedef short bf16x8 __attribute__((ext_vector_type(8)));
typedef float f32x4 __attribute__((ext_vector_type(4)));
typedef int   i32x4 __attribute__((ext_vector_type(4)));

__device__ __forceinline__ short f2b(float f) {
    __hip_bfloat16 h = __float2bfloat16(f);   // RNE
    return __builtin_bit_cast(short, h);
}
__device__ __forceinline__ float b2f(short s) {
    return __bfloat162float(__builtin_bit_cast(__hip_bfloat16, s));
}

// single-instruction lane swizzle (BitMode xor; works within 32-lane halves).
// DS-pipe op: overlaps with other waves' VALU work (measured r8 vs r10: beats DPP).
#define SWZF(v, pat) __builtin_bit_cast(float, __builtin_amdgcn_ds_swizzle(__builtin_bit_cast(int, v), pat))

#define C04L2E 0.5770780163555854f   // 0.4 * log2(e)
#define C06L2E 0.8656170245333781f   // 0.6 * log2(e)
#define DEFER_THR 8.0f               // defer-max threshold (log2 units)

// ---------------- CSR build ----------------
// hist: 4 edges per thread (int4 load)
__global__ void hist_kernel(const int* __restrict__ dst, int* __restrict__ counts) {
    int q = blockIdx.x * 256 + threadIdx.x;
    if (q < NE / 4) {
        i32x4 d = *reinterpret_cast<const i32x4*>(dst + q * 4);
#pragma unroll
        for (int k = 0; k < 4; ++k) atomicAdd(&counts[d[k]], 1);
    }
}

// scan1 fused with pack_w: blocks [0,49) do the block-local scan; blocks >= 49 pack weights.
__global__ __launch_bounds__(1024) void scan1_pack_kernel(
    int* __restrict__ counts, int* __restrict__ blocksum, int nblk,
    const float* __restrict__ Wl1, const float* __restrict__ Wr1,
    const float* __restrict__ Wl2, const float* __restrict__ Wr2,
    const float* __restrict__ Wmu, const float* __restrict__ Wlv,
    const float* __restrict__ bmu, const float* __restrict__ blv,
    short* __restrict__ Wb1t, short* __restrict__ Wb2t,
    short* __restrict__ Wb3t, float* __restrict__ bias3)
{
    if ((int)blockIdx.x >= nblk) {
        // ---- pack weights to bf16, TRANSPOSED: Wbt[n][k] = W[k][n] ----
        int i = (blockIdx.x - nblk) * 1024 + threadIdx.x;
        const int S1 = 512 * 256, S2 = 2 * S1, S3 = S2 + 128 * 256;
        if (i < S1) {
            int c = i >> 8, k = i & 255;
            float v = (c < 256) ? Wl1[k * 256 + c] : Wr1[k * 256 + (c - 256)];
            Wb1t[i] = f2b(v);
        } else if (i < S2) {
            int j = i - S1; int c = j >> 8, k = j & 255;
            float v = (c < 256) ? Wl2[k * 256 + c] : Wr2[k * 256 + (c - 256)];
            Wb2t[j] = f2b(v);
        } else if (i < S3) {
            int j = i - S2; int c = j >> 8, k = j & 255;
            float v = (c < 64) ? Wmu[k * 64 + c] : Wlv[k * 64 + (c - 64)];
            Wb3t[j] = f2b(v);
        } else if (i < S3 + 128) {
            int c = i - S3;
            bias3[c] = (c < 64) ? bmu[c] : blv[c - 64];
        }
        return;
    }
    // ---- block-local exclusive scan of counts; emit block sums ----
    const int g = blockIdx.x * 1024 + threadIdx.x;
    const int lane = threadIdx.x & 63;
    const int wv = threadIdx.x >> 6;            // 0..15
    int v = (g < NN) ? counts[g] : 0;
    int s = v;
#pragma unroll
    for (int d = 1; d < 64; d <<= 1) {
        int t = __shfl_up(s, d, 64);
        if (lane >= d) s += t;
    }
    __shared__ int wsum[16];
    if (lane == 63) wsum[wv] = s;
    __syncthreads();
    if (threadIdx.x == 0) {
        int run = 0;
#pragma unroll
        for (int q = 0; q < 16; ++q) { int t = wsum[q]; wsum[q] = run; run += t; }
        blocksum[blockIdx.x] = run;
    }
    __syncthreads();
    int excl = s - v + wsum[wv];
    if (g < NN) counts[g] = excl;
}

// scan3 with folded block-base: each block reduces blocksum[0..blockIdx-1] (nblk=49<=64).
__global__ __launch_bounds__(1024) void scan3_kernel(const int* __restrict__ counts,
                                                     const int* __restrict__ blocksum,
                                                     int* __restrict__ offsets,
                                                     int* __restrict__ cursor) {
    const int lane = threadIdx.x & 63;
    int v = (lane < blockIdx.x) ? blocksum[lane] : 0;
#pragma unroll
    for (int d = 32; d; d >>= 1) v += __shfl_xor(v, d, 64);
    const int g = blockIdx.x * 1024 + threadIdx.x;
    if (g < NN) {
        int o = counts[g] + v;
        offsets[g] = o;
        cursor[g]  = o;
    }
    if (blockIdx.x == 0 && threadIdx.x == 0) offsets[NN] = NE;
}

// scatter: 4 edges per thread (int4 loads of src & dst)
__global__ void scatter_kernel(const int* __restrict__ src, const int* __restrict__ dst,
                               int* __restrict__ cursor, int* __restrict__ csr_src) {
    int q = blockIdx.x * 256 + threadIdx.x;
    if (q < NE / 4) {
        i32x4 sv = *reinterpret_cast<const i32x4*>(src + q * 4);
        i32x4 dv = *reinterpret_cast<const i32x4*>(dst + q * 4);
#pragma unroll
        for (int k = 0; k < 4; ++k) {
            int p = atomicAdd(&cursor[dv[k]], 1);
            csr_src[p] = sv[k];
        }
    }
}

// ---------------- GEMM: A[M,256] @ W[256,Nc], Wbt[Nc,256] transposed ----------------
// 128-row blocks; A frags (2 row-groups) in registers; loop over NCT 64-col LDS sub-tiles.
// Register double-buffered B staging; OPERAND-SWAPPED MFMA (lane row = lane&15,
// cols = kq*4 + r consecutive) -> vectorized epilogue. ATT=1: fused att_pre.
template<int A_F32, int OUT_MODE, int NCT, int ATT>
__global__ __launch_bounds__(256) void gemm_k(
    const void* __restrict__ Ap, const short* __restrict__ Wbt,
    void* __restrict__ outp, const float* __restrict__ bias,
    const float* __restrict__ att, float* __restrict__ a_arr, int Nc)
{
    __shared__ short Bs[64 * 256];   // 32 KB, XOR-swizzled chunks (chunk = 8 shorts = 16B)
    const int t = threadIdx.x;
    const int w = t >> 6, lane = t & 63;
    const int row0 = blockIdx.x * 128;
    const int arow = lane & 15, kq = lane >> 4;
    const int xorc = arow & 7;

    // load A fragments once: rows w*32+arow and w*32+16+arow, k-chunks kc*32 + kq*8
    bf16x8 af[2][8];
    {
        int r0 = row0 + w * 32 + arow;      if (r0 > NN - 1) r0 = NN - 1;
        int r1 = row0 + w * 32 + 16 + arow; if (r1 > NN - 1) r1 = NN - 1;
        if (A_F32) {
            const float* A = (const float*)Ap;
            const float* b0 = A + (long)r0 * 256 + kq * 8;
            const float* b1 = A + (long)r1 * 256 + kq * 8;
#pragma unroll
            for (int kc = 0; kc < 8; ++kc) {
                const f32x4* q0 = reinterpret_cast<const f32x4*>(b0 + kc * 32);
                const f32x4* q1 = reinterpret_cast<const f32x4*>(b1 + kc * 32);
                f32x4 u0 = q0[0], u1 = q0[1], v0 = q1[0], v1 = q1[1];
#pragma unroll
                for (int j = 0; j < 4; ++j) {
                    af[0][kc][j] = f2b(u0[j]); af[0][kc][4 + j] = f2b(u1[j]);
                    af[1][kc][j] = f2b(v0[j]); af[1][kc][4 + j] = f2b(v1[j]);
                }
            }
        } else {
            const short* A = (const short*)Ap;
            const short* b0 = A + (long)r0 * 256 + kq * 8;
            const short* b1 = A + (long)r1 * 256 + kq * 8;
#pragma unroll
            for (int kc = 0; kc < 8; ++kc) {
                af[0][kc] = *reinterpret_cast<const bf16x8*>(b0 + kc * 32);
                af[1][kc] = *reinterpret_cast<const bf16x8*>(b1 + kc * 32);
            }
        }
    }

    const int sn = t >> 2;           // staging row 0..63
    const int cq = t & 3;            // 4 threads per row
    const int sx = sn & 7;
    short* bp = &Bs[sn * 256];

    // prologue: load ct=0 B sub-panel into registers
    bf16x8 breg[8];
    {
        const short* wp = Wbt + (long)sn * 256;
#pragma unroll
        for (int r = 0; r < 8; ++r)
            breg[r] = *reinterpret_cast<const bf16x8*>(wp + (cq + r * 4) * 8);
    }

#pragma unroll 1
    for (int ct = 0; ct < NCT; ++ct) {
        // write staged regs to LDS (swizzled)
#pragma unroll
        for (int r = 0; r < 8; ++r) {
            int c = cq + r * 4;
            *reinterpret_cast<bf16x8*>(bp + ((c ^ sx) * 8)) = breg[r];
        }
        __syncthreads();

        // prefetch next ct's panel (latency hides under MFMAs below)
        if (ct + 1 < NCT) {
            const short* wp = Wbt + (long)((ct + 1) * 64 + sn) * 256;
#pragma unroll
            for (int r = 0; r < 8; ++r)
                breg[r] = *reinterpret_cast<const bf16x8*>(wp + (cq + r * 4) * 8);
        }

        f32x4 acc[2][4];
#pragma unroll
        for (int rb = 0; rb < 2; ++rb)
#pragma unroll
            for (int b = 0; b < 4; ++b) acc[rb][b] = (f32x4){0.f, 0.f, 0.f, 0.f};

#pragma unroll
        for (int kc = 0; kc < 8; ++kc) {
            const int chunk = (kc * 4 + kq) ^ xorc;
#pragma unroll
            for (int nt = 0; nt < 4; ++nt) {
                bf16x8 b = *reinterpret_cast<const bf16x8*>(&Bs[(nt * 16 + arow) * 256 + chunk * 8]);
                // swapped operands: D^T layout -> lane row = arow, cols = kq*4 + r
                acc[0][nt] = __builtin_amdgcn_mfma_f32_16x16x32_bf16(b, af[0][kc], acc[0][nt], 0, 0, 0);
                acc[1][nt] = __builtin_amdgcn_mfma_f32_16x16x32_bf16(b, af[1][kc], acc[1][nt], 0, 0, 0);
            }
        }

        // fused att_pre: ct<4 covers xl head ct; lane holds row arow, cols nt*16+kq*4+r
        if (ATT && ct < 4) {
#pragma unroll
            for (int rb = 0; rb < 2; ++rb) {
                float pd = 0.f;
#pragma unroll
                for (int nt = 0; nt < 4; ++nt) {
                    f32x4 avv = *reinterpret_cast<const f32x4*>(att + ct * 64 + nt * 16 + kq * 4);
#pragma unroll
                    for (int r = 0; r < 4; ++r) pd = fmaf(avv[r], acc[rb][nt][r], pd);
                }
                pd += SWZF(pd, 0x401F);          // xor 16 (combine kq 0<->1, 2<->3)
                pd += __shfl_xor(pd, 32, 64);    // xor 32
                int grow = row0 + w * 32 + rb * 16 + arow;
                if (lane < 16 && grow < NN) a_arr[grow * 4 + ct] = pd * C06L2E;
            }
        }

        // write out: lane row = arow, 4 consecutive cols = nt*16 + kq*4 + (0..3)
#pragma unroll
        for (int rb = 0; rb < 2; ++rb) {
            int grow = row0 + w * 32 + rb * 16 + arow;
            if (grow < NN) {
#pragma unroll
                for (int nt = 0; nt < 4; ++nt) {
                    int gc0 = ct * 64 + nt * 16 + kq * 4;
                    if (OUT_MODE == 0) {
                        bf16x4 o;
#pragma unroll
                        for (int r = 0; r < 4; ++r) o[r] = f2b(acc[rb][nt][r]);
                        *reinterpret_cast<bf16x4*>((short*)outp + (long)grow * Nc + gc0) = o;
                    } else {
                        f32x4 bv = *reinterpret_cast<const f32x4*>(bias + gc0);
                        f32x4 o;
#pragma unroll
                        for (int r = 0; r < 4; ++r) o[r] = acc[rb][nt][r] + bv[r];
                        float* ob = (float*)outp;
                        if (gc0 < 64) *reinterpret_cast<f32x4*>(ob + (long)grow * 64 + gc0) = o;
                        else *reinterpret_cast<f32x4*>(ob + (long)NN * 64 + (long)grow * 64 + (gc0 - 64)) = o;
                    }
                }
            }
        }
        __syncthreads();   // Bs reads done before next stage write
    }
}

// ---------------- fused GATv2 v2 + index prefetch (ds_swizzle reduce — measured fastest) ----------------
// score (log2 domain, dst-constant term dropped): s = a[j][h] + sum_c (0.4*log2e*att_c)*|xl_jc+xr_ic|
__device__ __forceinline__ void edge_abs_score(const short* __restrict__ xlr, int j, int c4,
                                               const float* xr, const f32x4& attv04,
                                               float* xf, float& s) {
    bf16x4 v = *reinterpret_cast<const bf16x4*>(xlr + (long)j * 512 + c4);
    s = 0.f;
#pragma unroll
    for (int k = 0; k < 4; ++k) {
        xf[k] = b2f(v[k]);
        float vv = xf[k] + xr[k];
        s = fmaf(attv04[k], fabsf(vv), s);   // abs = free input modifier
    }
    // 16-lane head-group reduce: xor 1,2,4,8 (DS pipe, overlaps other waves' VALU)
    s += SWZF(s, 0x041F);
    s += SWZF(s, 0x081F);
    s += SWZF(s, 0x101F);
    s += SWZF(s, 0x201F);
}

__global__ __launch_bounds__(256) void gat_node_kernel(
    const short* __restrict__ xlr, const float* __restrict__ aarr,
    const int* __restrict__ offsets, const int* __restrict__ csr_src,
    const float* __restrict__ att, const float* __restrict__ bias,
    const float* __restrict__ ln_g, const float* __restrict__ ln_b,
    short* __restrict__ hout)
{
    const int i = blockIdx.x * 4 + (threadIdx.x >> 6);
    const int lane = threadIdx.x & 63;
    const int h  = lane >> 4;
    const int c4 = h * 64 + (lane & 15) * 4;   // head*64 + 4 channels

    f32x4 attv04 = *reinterpret_cast<const f32x4*>(att + c4);
#pragma unroll
    for (int k = 0; k < 4; ++k) attv04[k] *= C04L2E;

    float xr[4];
    {
        bf16x4 v = *reinterpret_cast<const bf16x4*>(xlr + (long)i * 512 + 256 + c4);
#pragma unroll
        for (int k = 0; k < 4; ++k) xr[k] = b2f(v[k]);
    }

    const int p0 = offsets[i], p1 = offsets[i + 1];

    // prefetch first pass's indices (clamped, branchless)
    int pp = p0 + (lane & 3);
    int jl = csr_src[pp < NE ? pp : NE - 1];

    float m, l;
    float acc[4];
    // self loop first
    {
        float aj = aarr[i * 4 + h];
        float xf[4], s;
        edge_abs_score(xlr, i, c4, xr, attv04, xf, s);
        m = s + aj; l = 1.f;
#pragma unroll
        for (int k = 0; k < 4; ++k) acc[k] = xf[k];
    }

    int p = p0;
    for (; p + 4 <= p1; p += 4) {
        int j0 = __builtin_amdgcn_readlane(jl, 0);
        int j1 = __builtin_amdgcn_readlane(jl, 1);
        int j2 = __builtin_amdgcn_readlane(jl, 2);
        int j3 = __builtin_amdgcn_readlane(jl, 3);
        // prefetch next pass (or tail) indices while this pass computes
        int pn = p + 4 + (lane & 3);
        jl = csr_src[pn < p1 ? pn : (p1 > 0 ? p1 - 1 : 0)];
        float a0 = aarr[j0 * 4 + h], a1 = aarr[j1 * 4 + h];
        float a2 = aarr[j2 * 4 + h], a3 = aarr[j3 * 4 + h];
        float x0[4], x1[4], x2[4], x3[4], s0, s1, s2, s3;
        edge_abs_score(xlr, j0, c4, xr, attv04, x0, s0);
        edge_abs_score(xlr, j1, c4, xr, attv04, x1, s1);
        edge_abs_score(xlr, j2, c4, xr, attv04, x2, s2);
        edge_abs_score(xlr, j3, c4, xr, attv04, x3, s3);
        s0 += a0; s1 += a1; s2 += a2; s3 += a3;
        float sm = fmaxf(fmaxf(s0, s1), fmaxf(s2, s3));
        if (__all(sm <= m + DEFER_THR)) {
            float e0 = __builtin_amdgcn_exp2f(s0 - m);
            float e1 = __builtin_amdgcn_exp2f(s1 - m);
            float e2 = __builtin_amdgcn_exp2f(s2 - m);
            float e3 = __builtin_amdgcn_exp2f(s3 - m);
            l += (e0 + e1) + (e2 + e3);
#pragma unroll
            for (int k = 0; k < 4; ++k)
                acc[k] = fmaf(e0, x0[k], fmaf(e1, x1[k], fmaf(e2, x2[k], fmaf(e3, x3[k], acc[k]))));
        } else {
            float mn = fmaxf(m, sm);
            float corr = __builtin_amdgcn_exp2f(m - mn);
            float e0 = __builtin_amdgcn_exp2f(s0 - mn);
            float e1 = __builtin_amdgcn_exp2f(s1 - mn);
            float e2 = __builtin_amdgcn_exp2f(s2 - mn);
            float e3 = __builtin_amdgcn_exp2f(s3 - mn);
            l = fmaf(l, corr, (e0 + e1) + (e2 + e3));
#pragma unroll
            for (int k = 0; k < 4; ++k)
                acc[k] = fmaf(acc[k], corr,
                         fmaf(e0, x0[k], fmaf(e1, x1[k], fmaf(e2, x2[k], e3 * x3[k]))));
            m = mn;
        }
    }
    // tail 0..3 edges: indices already resident in jl (lanes 0..rem-1)
    int rem = p1 - p;
    for (int tq = 0; tq < rem; ++tq) {
        int j = __builtin_amdgcn_readlane(jl, tq);
        float aj = aarr[j * 4 + h];
        float xa[4], sa;
        edge_abs_score(xlr, j, c4, xr, attv04, xa, sa);
        sa += aj;
        if (__all(sa <= m + DEFER_THR)) {
            float ex = __builtin_amdgcn_exp2f(sa - m);
            l += ex;
#pragma unroll
            for (int k = 0; k < 4; ++k) acc[k] = fmaf(ex, xa[k], acc[k]);
        } else {
            float mn = fmaxf(m, sa);
            float corr = __builtin_amdgcn_exp2f(m - mn);
            float ex = __builtin_amdgcn_exp2f(sa - mn);
            l = fmaf(l, corr, ex);
#pragma unroll
            for (int k = 0; k < 4; ++k) acc[k] = fmaf(acc[k], corr, ex * xa[k]);
            m = mn;
        }
    }

    float inv = 1.f / l;
    f32x4 bv = *reinterpret_cast<const f32x4*>(bias + c4);
    float out[4], s1 = 0.f, s2 = 0.f;
#pragma unroll
    for (int k = 0; k < 4; ++k) {
        out[k] = acc[k] * inv + bv[k];
        s1 += out[k];
        s2 += out[k] * out[k];
    }
    // LN over 256 channels: full-wave butterfly (swizzle xor 1..16, shfl xor 32)
    s1 += SWZF(s1, 0x041F); s2 += SWZF(s2, 0x041F);
    s1 += SWZF(s1, 0x081F); s2 += SWZF(s2, 0x081F);
    s1 += SWZF(s1, 0x101F); s2 += SWZF(s2, 0x101F);
    s1 += SWZF(s1, 0x201F); s2 += SWZF(s2, 0x201F);
    s1 += SWZF(s1, 0x401F); s2 += SWZF(s2, 0x401F);
    s1 += __shfl_xor(s1, 32, 64);
    s2 += __shfl_xor(s2, 32, 64);
    float mu  = s1 * (1.f / 256.f);
    float var = s2 * (1.f / 256.f) - mu * mu;
    float rs  = rsqrtf(var + 1e-5f);
    f32x4 gv  = *reinterpret_cast<const f32x4*>(ln_g + c4);
    f32x4 bbv = *reinterpret_cast<const f32x4*>(ln_b + c4);
    bf16x4 o;
#pragma unroll
    for (int k = 0; k < 4; ++k) {
        float y = (out[k] - mu) * rs * gv[k] + bbv[k];
        y = y > 0.f ? y : expm1f(y);                    // ELU
        o[k] = f2b(y);
    }
    *reinterpret_cast<bf16x4*>(hout + (long)i * 256 + c4) = o;
}

// ---------------- launch ----------------
extern "C" void kernel_launch(void* const* d_in, const int* in_sizes, int n_in,
                              void* d_out, int out_size, void* d_ws, size_t ws_size,
                              hipStream_t stream) {
    const float* x    = (const float*)d_in[0];
    const int*   ei   = (const int*)d_in[1];
    const float* Wl1  = (const float*)d_in[2];
    const float* Wr1  = (const float*)d_in[3];
    const float* att1 = (const float*)d_in[4];
    const float* b1   = (const float*)d_in[5];
    const float* ln1g = (const float*)d_in[6];
    const float* ln1b = (const float*)d_in[7];
    const float* Wl2  = (const float*)d_in[8];
    const float* Wr2  = (const float*)d_in[9];
    const float* att2 = (const float*)d_in[10];
    const float* b2   = (const float*)d_in[11];
    const float* ln2g = (const float*)d_in[12];
    const float* ln2b = (const float*)d_in[13];
    const float* Wmu  = (const float*)d_in[14];
    const float* bmu  = (const float*)d_in[15];
    const float* Wlv  = (const float*)d_in[16];
    const float* blv  = (const float*)d_in[17];

    // workspace layout
    short* bufXL = (short*)d_ws;                       // [N,512] bf16 (xl|xr)
    short* bufH  = bufXL + (long)NN * 512;             // [N,256] bf16 (h)
    short* Wb1t  = bufH + (long)NN * 256;              // 512*256
    short* Wb2t  = Wb1t + 512 * 256;
    short* Wb3t  = Wb2t + 512 * 256;                   // 128*256
    float* bias3 = (float*)(Wb3t + 128 * 256);         // 128
    int* counts  = (int*)(bias3 + 128);
    int* offsets = counts + NN;                        // N+1
    int* cursor  = offsets + NN + 1;
    int* csr_src = cursor + NN;                        // E
    int* blocksum = csr_src + NE;                      // 64
    float* a_arr = (float*)(blocksum + 64);            // [N,4]

    const int* src = ei;
    const int* dst = ei + NE;

    const int NBLK = (NN + 1023) / 1024;               // 49
    const int PACK_TOTAL = 2 * 512 * 256 + 128 * 256 + 128;
    const int PACK_BLK = (PACK_TOTAL + 1023) / 1024;   // 289

    // CSR by dst (parallel scan; pack fused with scan1; scan2 folded into scan3)
    hipMemsetAsync(counts, 0, NN * sizeof(int), stream);
    hist_kernel<<<(NE / 4 + 255) / 256, 256, 0, stream>>>(dst, counts);
    scan1_pack_kernel<<<NBLK + PACK_BLK, 1024, 0, stream>>>(
        counts, blocksum, NBLK,
        Wl1, Wr1, Wl2, Wr2, Wmu, Wlv, bmu, blv, Wb1t, Wb2t, Wb3t, bias3);
    scan3_kernel<<<NBLK, 1024, 0, stream>>>(counts, blocksum, offsets, cursor);
    scatter_kernel<<<(NE / 4 + 255) / 256, 256, 0, stream>>>(src, dst, cursor, csr_src);

    const int GM = (NN + 127) / 128;   // 391 row-blocks

    // layer 1 (A = x in f32, converted in-register; att_pre fused)
    gemm_k<1, 0, 8, 1><<<GM, 256, 0, stream>>>(x, Wb1t, bufXL, nullptr, att1, a_arr, 512);
    gat_node_kernel<<<NN / 4, 256, 0, stream>>>(bufXL, a_arr, offsets, csr_src,
                                                att1, b1, ln1g, ln1b, bufH);
    // layer 2
    gemm_k<0, 0, 8, 1><<<GM, 256, 0, stream>>>(bufH, Wb2t, bufXL, nullptr, att2, a_arr, 512);
    gat_node_kernel<<<NN / 4, 256, 0, stream>>>(bufXL, a_arr, offsets, csr_src,
                                                att2, b2, ln2g, ln2b, bufH);
    // heads: [mu|logvar]
    gemm_k<0, 1, 2, 0><<<GM, 256, 0, stream>>>(bufH, Wb3t, d_out, bias3, nullptr, nullptr, 128);
}